// Round 2
// baseline (462.154 us; speedup 1.0000x reference)
//
#include <hip/hip_runtime.h>
#include <hip/hip_bf16.h>
#include <stdint.h>

#define B_  32
#define L_  128
#define D_  300
#define DP_ 304
#define H_  128
#define G_  512
#define E_  34
#define A_  36
#define M_  4096   // B*L
#define NC_ 106    // 34 ev + 36 base + 36 t2
#define NCP 112    // padded col count
#define CH_ 8      // scan chunk length
#define NCH 16     // chunks per sequence
#define LCH 8      // lstm xw prefetch chunk length

__device__ __forceinline__ float sigf(float x){ return 1.0f / (1.0f + expf(-x)); }

// ---- P1: transpose W_ih into WT[d][k][n] (k-major, zero-padded k<304) ----
__global__ void k_prep1(const float* __restrict__ wihf, const float* __restrict__ wihb,
                        float* __restrict__ WT){
    int k = blockIdx.x;            // 0..303
    int d = blockIdx.y;            // 0..1
    int n = threadIdx.x;           // 0..511
    const float* w = d ? wihb : wihf;
    WT[((size_t)d * DP_ + k) * G_ + n] = (k < D_) ? w[(size_t)n * D_ + k] : 0.0f;
}

// ---- P2: pack head weights WcatT[k][n] (256 x NCP) + bias vector ----
__global__ void k_prep2(const float* __restrict__ evw, const float* __restrict__ evb,
                        const float* __restrict__ argw, const float* __restrict__ argb,
                        float* __restrict__ WcatT, float* __restrict__ biasv){
    int k = blockIdx.x;            // 0..255
    int n = threadIdx.x;           // 0..127
    if (n >= NCP) return;          // guard: block 128 wide, row 112
    float v = 0.0f;
    if (n < E_)       v = evw[(size_t)n * 256 + k];
    else if (n < 70)  v = argw[(size_t)(n - 34) * 545 + k];
    else if (n < NC_) v = argw[(size_t)(n - 70) * 545 + 256 + k];
    WcatT[(size_t)k * NCP + n] = v;
    if (k == 0){
        float bv = 0.0f;
        if (n < E_) bv = evb[n];
        else if (n < 70) bv = argb[n - 34];
        biasv[n] = bv;
    }
}

// ---- G1: XW[d][m][n] = emb[ids[m]][:] . w_ih_d[n][:] + b_ih[n] + b_hh[n] ----
// Round-8 retile: 256 threads, 2 cols/thread, xs transposed to [k][r] so the
// per-k LDS traffic is 2x ds_read_b128 (was 8x scalar ds_read_b32) feeding
// 16 FMAs -> VALU-bound instead of LDS-issue-bound.
__launch_bounds__(256)
__global__ void k_gemm1(const int* __restrict__ ids, const float* __restrict__ emb,
                        const float* __restrict__ WT,
                        const float* __restrict__ bihf, const float* __restrict__ bhhf,
                        const float* __restrict__ bihb, const float* __restrict__ bhhb,
                        float* __restrict__ XW){
    __shared__ __align__(16) float xs[DP_][8];   // [k][r]
    int d  = blockIdx.y;
    int m0 = blockIdx.x * 8;
    int tid = threadIdx.x;         // 0..255
    for (int idx = tid; idx < 8 * DP_; idx += 256){
        int r = idx / DP_, k = idx % DP_;
        int id = ids[m0 + r];
        xs[k][r] = (k < D_) ? emb[(size_t)id * D_ + k] : 0.0f;
    }
    __syncthreads();
    int n0 = tid, n1 = tid + 256;
    const float* w0 = WT + (size_t)d * DP_ * G_ + n0;
    const float* w1 = WT + (size_t)d * DP_ * G_ + n1;
    const float4* xs4 = (const float4*)xs;
    float acc0[8] = {}, acc1[8] = {};
    #pragma unroll 2
    for (int k = 0; k < D_; k++){
        float wv0 = w0[(size_t)k * G_];
        float wv1 = w1[(size_t)k * G_];
        float4 xA = xs4[k * 2], xB = xs4[k * 2 + 1];
        acc0[0] += xA.x * wv0; acc0[1] += xA.y * wv0;
        acc0[2] += xA.z * wv0; acc0[3] += xA.w * wv0;
        acc0[4] += xB.x * wv0; acc0[5] += xB.y * wv0;
        acc0[6] += xB.z * wv0; acc0[7] += xB.w * wv0;
        acc1[0] += xA.x * wv1; acc1[1] += xA.y * wv1;
        acc1[2] += xA.z * wv1; acc1[3] += xA.w * wv1;
        acc1[4] += xB.x * wv1; acc1[5] += xB.y * wv1;
        acc1[6] += xB.z * wv1; acc1[7] += xB.w * wv1;
    }
    float bias0 = d ? (bihb[n0] + bhhb[n0]) : (bihf[n0] + bhhf[n0]);
    float bias1 = d ? (bihb[n1] + bhhb[n1]) : (bihf[n1] + bhhf[n1]);
    for (int r = 0; r < 8; r++){
        XW[((size_t)d * M_ + m0 + r) * G_ + n0] = acc0[r] + bias0;
        XW[((size_t)d * M_ + m0 + r) * G_ + n1] = acc1[r] + bias1;
    }
}

// ---- K3: LSTM recurrence. 64 blocks = (dir,b); 256 threads x 2 rows each.
// Round-8 restructure (round-7 was LDS-issue-bound: 512 threads re-reading h
// = 64x ds_read_b128 per SIMD per step = 768 cyc > 512 cyc FMA):
//  (1) 256 threads, each owns rows (t, t+256) -> h read ONCE per thread per
//      step (32x b128, 384 cyc/SIMD) feeding 256 FMAs (512 cyc) -> VALU-bound.
//  (2) gate pairing: t<128 owns (i,g) in regs; t>=128 owns (f,o), publishes
//      via 256-float zbuf -> phase B = 2 LDS reads + c/h update.
//  (3) W_hh rows in VGPRs (256 regs); __launch_bounds__(256,1) caps at 512.
//  (4) full 128-step h history in LDS (64 KB), single bulk flush at end.
// Numerically identical to round-7 (same FMA grouping, same gate formulas).
#define STEP(S_, XA, XB)                                                        \
{                                                                               \
    float a0=0.f,a1=0.f,a2=0.f,a3=0.f,b0=0.f,b1=0.f,b2=0.f,b3=0.f;              \
    const float4* hc = (const float4*)hbuf;                                     \
    _Pragma("unroll")                                                           \
    for (int q = 0; q < 32; q++){                                               \
        float4 hv = hc[q];                                                      \
        a0 += wA[q].x * hv.x; a1 += wA[q].y * hv.y;                             \
        a2 += wA[q].z * hv.z; a3 += wA[q].w * hv.w;                             \
        b0 += wB[q].x * hv.x; b1 += wB[q].y * hv.y;                             \
        b2 += wB[q].z * hv.z; b3 += wB[q].w * hv.w;                             \
    }                                                                           \
    float zA = (XA) + ((a0 + a1) + (a2 + a3));                                  \
    float zB = (XB) + ((b0 + b1) + (b2 + b3));                                  \
    float vA = sigf(zA);                                                        \
    float vB = gl ? tanhf(zB) : sigf(zB);                                       \
    if (!gl){ zbuf[t0 - H_] = vA; zbuf[t0] = vB; }                              \
    __syncthreads();                                                            \
    if (gl){                                                                    \
        float F = zbuf[t0], O = zbuf[H_ + t0];                                  \
        c = F * c + vA * vB;                                                    \
        float h = O * tanhf(c);                                                 \
        hbuf[t0] = h;                                                           \
        hist[(size_t)(S_) * H_ + t0] = h;                                       \
    }                                                                           \
    __syncthreads();                                                            \
}

__launch_bounds__(256, 1)
__global__ void k_lstm(const float* __restrict__ XW, const float* __restrict__ whhf,
                       const float* __restrict__ whhb, float* __restrict__ Hid){
    __shared__ __align__(16) float hbuf[H_];
    __shared__ float zbuf[2 * H_];                  // F,O published by upper threads
    __shared__ __align__(16) float hist[L_ * H_];   // 64 KB full h history
    int bid = blockIdx.x;
    int d = bid >> 5, b = bid & 31;
    int t0 = threadIdx.x;          // 0..255; rows t0 (i/f) and t0+256 (g/o)
    bool gl = (t0 < H_);           // lower half: owns (i,g); upper: (f,o)
    const float* whh = d ? whhb : whhf;
    const float4* wrA = (const float4*)(whh + (size_t)t0 * H_);
    const float4* wrB = (const float4*)(whh + (size_t)(t0 + 256) * H_);
    float4 wA[32], wB[32];
    #pragma unroll
    for (int q = 0; q < 32; q++){ wA[q] = wrA[q]; wB[q] = wrB[q]; }
    float c = 0.0f;
    if (gl) hbuf[t0] = 0.0f;
    __syncthreads();
    const float* xwA = XW + ((size_t)d * M_ + (size_t)b * L_) * G_ + t0;
    const float* xwB = xwA + 256;
    #pragma unroll 1
    for (int ch = 0; ch < L_ / LCH; ch++){
        float xa[LCH], xb[LCH];
        #pragma unroll
        for (int j = 0; j < LCH; j++){
            int s_ = ch * LCH + j;
            int t_ = d ? (L_ - 1 - s_) : s_;
            xa[j] = xwA[(size_t)t_ * G_];
            xb[j] = xwB[(size_t)t_ * G_];
        }
        #pragma unroll
        for (int j = 0; j < LCH; j++){
            STEP(ch * LCH + j, xa[j], xb[j])
        }
    }
    // bulk flush: 128 steps x 128 h = 4096 float4, 16 per thread
    const float4* hist4 = (const float4*)hist;
    #pragma unroll
    for (int q = 0; q < 16; q++){
        int idx = t0 + q * 256;
        int sl = idx >> 5, n4 = idx & 31;
        int t_ = d ? (L_ - 1 - sl) : sl;
        *(float4*)(Hid + ((size_t)b * L_ + t_) * 256 + d * H_ + n4 * 4) =
            hist4[(size_t)sl * 32 + n4];
    }
}

// ---- K4: heads. One block per m. cols: 0..33 ev, 34..69 base, 70..105 t2. ----
__launch_bounds__(128)
__global__ void k_heads2(const float* __restrict__ Hid, const float* __restrict__ WcatT,
                         const float* __restrict__ biasv,
                         float* __restrict__ out0, float* __restrict__ Base,
                         float* __restrict__ T2, int* __restrict__ Evcol){
    __shared__ float hs[256];
    __shared__ float evl[E_];
    int m = blockIdx.x;
    int tid = threadIdx.x;         // 0..127
    hs[tid]       = Hid[(size_t)m * 256 + tid];
    hs[tid + 128] = Hid[(size_t)m * 256 + 128 + tid];
    __syncthreads();
    float acc = 0.0f;
    if (tid < NC_){
        const float* wc = WcatT + tid;
        for (int k = 0; k < 256; k++) acc += hs[k] * wc[(size_t)k * NCP];
        acc += biasv[tid];
    }
    if (tid < E_){
        out0[(size_t)m * E_ + tid] = acc;   // fp32 output
        evl[tid] = acc;
    } else if (tid < 70){
        Base[(size_t)m * A_ + (tid - 34)] = acc;
    } else if (tid < NC_){
        T2[(size_t)m * A_ + (tid - 70)] = acc;
    }
    __syncthreads();
    if (tid == 0){                 // first-max argmax over E=34
        float best = evl[0]; int bi = 0;
        for (int e = 1; e < E_; e++){
            float v = evl[e];
            if (v > best){ best = v; bi = e; }
        }
        Evcol[m] = bi - 1;         // -1 => ev_pred==0 (no g update)
    }
}

// ---- K5a: serial state propagation only. Snapshots (bg, mask) every CH_ steps.
// No argout stores here — that's phase 2's job.
__launch_bounds__(128)
__global__ void k_scan1(const float* __restrict__ Base, const float* __restrict__ T2,
                        const int* __restrict__ Evcol, const float* __restrict__ argw,
                        float* __restrict__ Snap, uint64_t* __restrict__ MaskSnap){
    __shared__ float t2s[L_ * A_];
    __shared__ float wgs[33 * A_];
    __shared__ int   evc[L_];
    int b = blockIdx.x;
    int l = threadIdx.x;             // 0..127
    for (int idx = l; idx < L_ * A_; idx += 128)
        t2s[idx] = T2[(size_t)b * L_ * A_ + idx];
    for (int idx = l; idx < 33 * A_; idx += 128){
        int c = idx / A_, a = idx % A_;
        wgs[idx] = argw[(size_t)a * 545 + 512 + c];
    }
    evc[l] = Evcol[b * L_ + l];
    __syncthreads();
    float bg[A_];
    {
        const float* bp = Base + ((size_t)b * L_ + l) * A_;
        #pragma unroll
        for (int a = 0; a < A_; a++) bg[a] = bp[a];
    }
    uint64_t mask = 0;
    #pragma unroll 1
    for (int i = 0; i < L_; i++){
        if ((i & (CH_ - 1)) == 0){
            int ch = i >> 3;
            float* sp = Snap + (((size_t)b * NCH + ch) * L_ + l) * A_;
            #pragma unroll
            for (int a = 0; a < A_; a++) sp[a] = bg[a];
            MaskSnap[((size_t)b * NCH + ch) * L_ + l] = mask;
        }
        const float* tr = t2s + i * A_;
        float lg0 = bg[0] + tr[0];
        float m1  = bg[1] + tr[1];
        #pragma unroll
        for (int a = 2; a < A_; a++) m1 = fmaxf(m1, bg[a] + tr[a]);
        bool apos = m1 > lg0;
        int cc = evc[i];
        if (cc >= 0 && apos && !((mask >> cc) & 1ull)){
            mask |= 1ull << cc;
            const float* wc = wgs + cc * A_;
            #pragma unroll
            for (int a = 0; a < A_; a++) bg[a] += wc[a];
        }
    }
}

// ---- K5b: parallel replay of CH_-step chunks from snapshots; does all stores.
// Bit-exact same ops as k_scan1 => identical decisions, exact state continuity.
__launch_bounds__(128)
__global__ void k_scan2(const float* __restrict__ T2, const int* __restrict__ Evcol,
                        const float* __restrict__ argw,
                        const float* __restrict__ Snap, const uint64_t* __restrict__ MaskSnap,
                        float* __restrict__ argout){
    __shared__ float t2s[CH_ * A_];
    __shared__ float wgs[33 * A_];
    __shared__ int   evc[CH_];
    int ch = blockIdx.x;             // 0..15
    int b  = blockIdx.y;             // 0..31
    int l  = threadIdx.x;            // 0..127
    int i0 = ch * CH_;
    for (int idx = l; idx < CH_ * A_; idx += 128)
        t2s[idx] = T2[((size_t)b * L_ + i0) * A_ + idx];
    for (int idx = l; idx < 33 * A_; idx += 128){
        int c = idx / A_, a = idx % A_;
        wgs[idx] = argw[(size_t)a * 545 + 512 + c];
    }
    if (l < CH_) evc[l] = Evcol[b * L_ + i0 + l];
    __syncthreads();
    float bg[A_];
    {
        const float* sp = Snap + (((size_t)b * NCH + ch) * L_ + l) * A_;
        #pragma unroll
        for (int a = 0; a < A_; a++) bg[a] = sp[a];
    }
    uint64_t mask = MaskSnap[((size_t)b * NCH + ch) * L_ + l];
    #pragma unroll 1
    for (int s = 0; s < CH_; s++){
        int i = i0 + s;
        const float* tr = t2s + s * A_;
        float lg[A_];
        #pragma unroll
        for (int a = 0; a < A_; a++) lg[a] = bg[a] + tr[a];
        float m1 = lg[1];
        #pragma unroll
        for (int a = 2; a < A_; a++) m1 = fmaxf(m1, lg[a]);
        bool apos = m1 > lg[0];
        float* op = argout + (((size_t)b * L_ + i) * L_ + l) * A_;
        #pragma unroll
        for (int q = 0; q < 9; q++){
            float4 v; v.x = lg[4*q]; v.y = lg[4*q+1]; v.z = lg[4*q+2]; v.w = lg[4*q+3];
            *(float4*)(op + 4 * q) = v;
        }
        int cc = evc[s];
        if (cc >= 0 && apos && !((mask >> cc) & 1ull)){
            mask |= 1ull << cc;
            const float* wc = wgs + cc * A_;
            #pragma unroll
            for (int a = 0; a < A_; a++) bg[a] += wc[a];
        }
    }
}

extern "C" void kernel_launch(void* const* d_in, const int* in_sizes, int n_in,
                              void* d_out, int out_size, void* d_ws, size_t ws_size,
                              hipStream_t stream){
    const int*   ids  = (const int*)  d_in[0];
    const float* emb  = (const float*)d_in[1];
    const float* wihf = (const float*)d_in[2];
    const float* whhf = (const float*)d_in[3];
    const float* bihf = (const float*)d_in[4];
    const float* bhhf = (const float*)d_in[5];
    const float* wihb = (const float*)d_in[6];
    const float* whhb = (const float*)d_in[7];
    const float* bihb = (const float*)d_in[8];
    const float* bhhb = (const float*)d_in[9];
    const float* evw  = (const float*)d_in[10];
    const float* evb  = (const float*)d_in[11];
    const float* argw = (const float*)d_in[12];
    const float* argb = (const float*)d_in[13];

    float* out0   = (float*)d_out;                 // [B,L,E] fp32
    float* argout = out0 + (size_t)M_ * E_;        // [B,L,L,A] fp32

    char* w = (char*)d_ws;                          // ~23.5 MB total
    float* WT    = (float*)w; w += (size_t)2 * DP_ * G_ * 4;   // 1.24 MB
    float* XW    = (float*)w; w += (size_t)2 * M_ * G_ * 4;    // 16.78 MB
    float* Hid   = (float*)w; w += (size_t)M_ * 256 * 4;       // 4.19 MB
    float* WcatT = (float*)w; w += (size_t)256 * NCP * 4;
    float* biasv = (float*)w; w += (size_t)NCP * 4;
    float* Base  = (float*)w; w += (size_t)M_ * A_ * 4;
    float* T2    = (float*)w; w += (size_t)M_ * A_ * 4;
    int*   Evcol = (int*)w;   w += (size_t)M_ * 4;

    // Scan snapshots alias the XW region (dead after k_lstm):
    // Snap 9.44 MB + MaskSnap 0.5 MB < 16.78 MB.
    float*    Snap     = XW;
    uint64_t* MaskSnap = (uint64_t*)(XW + (size_t)B_ * NCH * L_ * A_);

    k_prep1<<<dim3(DP_, 2), 512, 0, stream>>>(wihf, wihb, WT);
    k_prep2<<<256, 128, 0, stream>>>(evw, evb, argw, argb, WcatT, biasv);
    k_gemm1<<<dim3(M_ / 8, 2), 256, 0, stream>>>(ids, emb, WT, bihf, bhhf, bihb, bhhb, XW);
    k_lstm<<<64, 256, 0, stream>>>(XW, whhf, whhb, Hid);
    k_heads2<<<M_, 128, 0, stream>>>(Hid, WcatT, biasv, out0, Base, T2, Evcol);
    k_scan1<<<B_, 128, 0, stream>>>(Base, T2, Evcol, argw, Snap, MaskSnap);
    k_scan2<<<dim3(NCH, B_), 128, 0, stream>>>(T2, Evcol, argw, Snap, MaskSnap, argout);
}

// Round 3
// 444.375 us; speedup vs baseline: 1.0400x; 1.0400x over previous
//
#include <hip/hip_runtime.h>
#include <hip/hip_bf16.h>
#include <stdint.h>

#define B_  32
#define L_  128
#define D_  300
#define DP_ 304
#define H_  128
#define G_  512
#define E_  34
#define A_  36
#define M_  4096   // B*L
#define NC_ 106    // 34 ev + 36 base + 36 t2
#define NCP 112    // padded col count
#define CH_ 8      // scan chunk length
#define NCH 16     // chunks per sequence
#define LCH 8      // lstm xw prefetch chunk length

__device__ __forceinline__ float sigf(float x){ return 1.0f / (1.0f + expf(-x)); }

// ---- P1: transpose W_ih into WT[d][k][n] (k-major, zero-padded k<304) ----
__global__ void k_prep1(const float* __restrict__ wihf, const float* __restrict__ wihb,
                        float* __restrict__ WT){
    int k = blockIdx.x;            // 0..303
    int d = blockIdx.y;            // 0..1
    int n = threadIdx.x;           // 0..511
    const float* w = d ? wihb : wihf;
    WT[((size_t)d * DP_ + k) * G_ + n] = (k < D_) ? w[(size_t)n * D_ + k] : 0.0f;
}

// ---- P2: pack head weights WcatT[k][n] (256 x NCP) + bias vector ----
__global__ void k_prep2(const float* __restrict__ evw, const float* __restrict__ evb,
                        const float* __restrict__ argw, const float* __restrict__ argb,
                        float* __restrict__ WcatT, float* __restrict__ biasv){
    int k = blockIdx.x;            // 0..255
    int n = threadIdx.x;           // 0..127
    if (n >= NCP) return;          // guard: block 128 wide, row 112
    float v = 0.0f;
    if (n < E_)       v = evw[(size_t)n * 256 + k];
    else if (n < 70)  v = argw[(size_t)(n - 34) * 545 + k];
    else if (n < NC_) v = argw[(size_t)(n - 70) * 545 + 256 + k];
    WcatT[(size_t)k * NCP + n] = v;
    if (k == 0){
        float bv = 0.0f;
        if (n < E_) bv = evb[n];
        else if (n < 70) bv = argb[n - 34];
        biasv[n] = bv;
    }
}

// ---- G1: XW[d][m][n] = emb[ids[m]][:] . w_ih_d[n][:] + b_ih[n] + b_hh[n] ----
// Round-8 retile (kept): 256 threads, 2 cols/thread, xs transposed to [k][r]:
// per-k LDS = 2x ds_read_b128 feeding 16 FMAs -> VALU-bound.
__launch_bounds__(256)
__global__ void k_gemm1(const int* __restrict__ ids, const float* __restrict__ emb,
                        const float* __restrict__ WT,
                        const float* __restrict__ bihf, const float* __restrict__ bhhf,
                        const float* __restrict__ bihb, const float* __restrict__ bhhb,
                        float* __restrict__ XW){
    __shared__ __align__(16) float xs[DP_][8];   // [k][r]
    int d  = blockIdx.y;
    int m0 = blockIdx.x * 8;
    int tid = threadIdx.x;         // 0..255
    for (int idx = tid; idx < 8 * DP_; idx += 256){
        int r = idx / DP_, k = idx % DP_;
        int id = ids[m0 + r];
        xs[k][r] = (k < D_) ? emb[(size_t)id * D_ + k] : 0.0f;
    }
    __syncthreads();
    int n0 = tid, n1 = tid + 256;
    const float* w0 = WT + (size_t)d * DP_ * G_ + n0;
    const float* w1 = WT + (size_t)d * DP_ * G_ + n1;
    const float4* xs4 = (const float4*)xs;
    float acc0[8] = {}, acc1[8] = {};
    #pragma unroll 2
    for (int k = 0; k < D_; k++){
        float wv0 = w0[(size_t)k * G_];
        float wv1 = w1[(size_t)k * G_];
        float4 xA = xs4[k * 2], xB = xs4[k * 2 + 1];
        acc0[0] += xA.x * wv0; acc0[1] += xA.y * wv0;
        acc0[2] += xA.z * wv0; acc0[3] += xA.w * wv0;
        acc0[4] += xB.x * wv0; acc0[5] += xB.y * wv0;
        acc0[6] += xB.z * wv0; acc0[7] += xB.w * wv0;
        acc1[0] += xA.x * wv1; acc1[1] += xA.y * wv1;
        acc1[2] += xA.z * wv1; acc1[3] += xA.w * wv1;
        acc1[4] += xB.x * wv1; acc1[5] += xB.y * wv1;
        acc1[6] += xB.z * wv1; acc1[7] += xB.w * wv1;
    }
    float bias0 = d ? (bihb[n0] + bhhb[n0]) : (bihf[n0] + bhhf[n0]);
    float bias1 = d ? (bihb[n1] + bhhb[n1]) : (bihf[n1] + bhhf[n1]);
    for (int r = 0; r < 8; r++){
        XW[((size_t)d * M_ + m0 + r) * G_ + n0] = acc0[r] + bias0;
        XW[((size_t)d * M_ + m0 + r) * G_ + n1] = acc1[r] + bias1;
    }
}

// ---- K3: LSTM recurrence. 64 blocks = (dir,b); 1024 threads.
// Round-9: K-split to keep weights in ARCH VGPRs (round-8 post-mortem: 252
// VGPRs => compiler moved 256-reg weight arrays to AGPRs, paying ~256
// v_accvgpr_read per step; round-7's VGPR=92 shows the same for wv[32]).
// Thread t owns (row = t>>1, K-half = t&1): 16 float4 = 64 weight VGPRs,
// total ~100 < 128 cap at launch_bounds(1024,4) -> no AGPR traffic, and
// 4 waves/SIMD for latency hiding. Halves combined via __shfl_xor(.,1)
// (adjacent lanes). Per step/SIMD: 512 cyc FMA, <=768 cyc LDS (overlapped).
// Phase B: even threads with row<128 keep I in-register, read F,G,O from zbuf.
#define STEP(S_, XWV)                                                           \
{                                                                               \
    float a0=0.f,a1=0.f,a2=0.f,a3=0.f;                                          \
    const float4* hc = (const float4*)hbuf + (half << 4);                       \
    _Pragma("unroll")                                                           \
    for (int q = 0; q < 16; q++){                                               \
        float4 hv = hc[q];                                                      \
        a0 += wv[q].x * hv.x; a1 += wv[q].y * hv.y;                             \
        a2 += wv[q].z * hv.z; a3 += wv[q].w * hv.w;                             \
    }                                                                           \
    float part  = (a0 + a1) + (a2 + a3);                                        \
    float other = __shfl_xor(part, 1);                                          \
    float v = 0.0f;                                                             \
    if (half == 0){                                                             \
        float z = ((XWV) + part) + other;                                       \
        v = gate_g ? tanhf(z) : sigf(z);                                        \
        zbuf[row] = v;                                                          \
    }                                                                           \
    __syncthreads();                                                            \
    if (pb){                                                                    \
        float F = zbuf[H_ + row], G = zbuf[2*H_ + row], O = zbuf[3*H_ + row];   \
        c = F * c + v * G;                                                      \
        float h = O * tanhf(c);                                                 \
        hbuf[row] = h;                                                          \
        hist[(size_t)(S_) * H_ + row] = h;                                      \
    }                                                                           \
    __syncthreads();                                                            \
}

__launch_bounds__(1024, 4)
__global__ void k_lstm(const float* __restrict__ XW, const float* __restrict__ whhf,
                       const float* __restrict__ whhb, float* __restrict__ Hid){
    __shared__ __align__(16) float hbuf[H_];
    __shared__ float zbuf[G_];                      // activated gate values
    __shared__ __align__(16) float hist[L_ * H_];   // 64 KB full h history
    int bid = blockIdx.x;
    int d = bid >> 5, b = bid & 31;
    int tid = threadIdx.x;         // 0..1023
    int row = tid >> 1;            // 0..511  (z-row)
    int half = tid & 1;            // K-half: 0 -> k 0..63, 1 -> k 64..127
    bool gate_g = (row >= 256) && (row < 384);   // wave-uniform (32 rows/wave)
    bool pb = (half == 0) && (row < H_);         // phase-B owner for n=row
    const float* whh = d ? whhb : whhf;
    const float4* wr = (const float4*)(whh + (size_t)row * H_ + half * 64);
    float4 wv[16];
    #pragma unroll
    for (int q = 0; q < 16; q++) wv[q] = wr[q];
    float c = 0.0f;
    if (tid < H_) hbuf[tid] = 0.0f;
    __syncthreads();
    const float* xwn = XW + ((size_t)d * M_ + (size_t)b * L_) * G_ + row;
    #pragma unroll 1
    for (int ch = 0; ch < L_ / LCH; ch++){
        float xr[LCH];
        #pragma unroll
        for (int j = 0; j < LCH; j++){
            int s_ = ch * LCH + j;
            int t_ = d ? (L_ - 1 - s_) : s_;
            xr[j] = xwn[(size_t)t_ * G_];   // lane pairs load same addr (ok)
        }
        #pragma unroll
        for (int j = 0; j < LCH; j++){
            STEP(ch * LCH + j, xr[j])
        }
    }
    // bulk flush: 128 steps x 128 h = 4096 float4, 4 per thread
    const float4* hist4 = (const float4*)hist;
    #pragma unroll
    for (int q = 0; q < 4; q++){
        int idx = tid + q * 1024;
        int sl = idx >> 5, n4 = idx & 31;
        int t_ = d ? (L_ - 1 - sl) : sl;
        *(float4*)(Hid + ((size_t)b * L_ + t_) * 256 + d * H_ + n4 * 4) =
            hist4[(size_t)sl * 32 + n4];
    }
}

// ---- K4: heads. One block per m. cols: 0..33 ev, 34..69 base, 70..105 t2. ----
__launch_bounds__(128)
__global__ void k_heads2(const float* __restrict__ Hid, const float* __restrict__ WcatT,
                         const float* __restrict__ biasv,
                         float* __restrict__ out0, float* __restrict__ Base,
                         float* __restrict__ T2, int* __restrict__ Evcol){
    __shared__ float hs[256];
    __shared__ float evl[E_];
    int m = blockIdx.x;
    int tid = threadIdx.x;         // 0..127
    hs[tid]       = Hid[(size_t)m * 256 + tid];
    hs[tid + 128] = Hid[(size_t)m * 256 + 128 + tid];
    __syncthreads();
    float acc = 0.0f;
    if (tid < NC_){
        const float* wc = WcatT + tid;
        for (int k = 0; k < 256; k++) acc += hs[k] * wc[(size_t)k * NCP];
        acc += biasv[tid];
    }
    if (tid < E_){
        out0[(size_t)m * E_ + tid] = acc;   // fp32 output
        evl[tid] = acc;
    } else if (tid < 70){
        Base[(size_t)m * A_ + (tid - 34)] = acc;
    } else if (tid < NC_){
        T2[(size_t)m * A_ + (tid - 70)] = acc;
    }
    __syncthreads();
    if (tid == 0){                 // first-max argmax over E=34
        float best = evl[0]; int bi = 0;
        for (int e = 1; e < E_; e++){
            float v = evl[e];
            if (v > best){ best = v; bi = e; }
        }
        Evcol[m] = bi - 1;         // -1 => ev_pred==0 (no g update)
    }
}

// ---- K5a: serial state propagation only. Snapshots (bg, mask) every CH_ steps.
// No argout stores here — that's phase 2's job.
__launch_bounds__(128)
__global__ void k_scan1(const float* __restrict__ Base, const float* __restrict__ T2,
                        const int* __restrict__ Evcol, const float* __restrict__ argw,
                        float* __restrict__ Snap, uint64_t* __restrict__ MaskSnap){
    __shared__ float t2s[L_ * A_];
    __shared__ float wgs[33 * A_];
    __shared__ int   evc[L_];
    int b = blockIdx.x;
    int l = threadIdx.x;             // 0..127
    for (int idx = l; idx < L_ * A_; idx += 128)
        t2s[idx] = T2[(size_t)b * L_ * A_ + idx];
    for (int idx = l; idx < 33 * A_; idx += 128){
        int c = idx / A_, a = idx % A_;
        wgs[idx] = argw[(size_t)a * 545 + 512 + c];
    }
    evc[l] = Evcol[b * L_ + l];
    __syncthreads();
    float bg[A_];
    {
        const float* bp = Base + ((size_t)b * L_ + l) * A_;
        #pragma unroll
        for (int a = 0; a < A_; a++) bg[a] = bp[a];
    }
    uint64_t mask = 0;
    #pragma unroll 1
    for (int i = 0; i < L_; i++){
        if ((i & (CH_ - 1)) == 0){
            int ch = i >> 3;
            float* sp = Snap + (((size_t)b * NCH + ch) * L_ + l) * A_;
            #pragma unroll
            for (int a = 0; a < A_; a++) sp[a] = bg[a];
            MaskSnap[((size_t)b * NCH + ch) * L_ + l] = mask;
        }
        const float* tr = t2s + i * A_;
        float lg0 = bg[0] + tr[0];
        float m1  = bg[1] + tr[1];
        #pragma unroll
        for (int a = 2; a < A_; a++) m1 = fmaxf(m1, bg[a] + tr[a]);
        bool apos = m1 > lg0;
        int cc = evc[i];
        if (cc >= 0 && apos && !((mask >> cc) & 1ull)){
            mask |= 1ull << cc;
            const float* wc = wgs + cc * A_;
            #pragma unroll
            for (int a = 0; a < A_; a++) bg[a] += wc[a];
        }
    }
}

// ---- K5b: parallel replay of CH_-step chunks from snapshots; does all stores.
// Bit-exact same ops as k_scan1 => identical decisions, exact state continuity.
__launch_bounds__(128)
__global__ void k_scan2(const float* __restrict__ T2, const int* __restrict__ Evcol,
                        const float* __restrict__ argw,
                        const float* __restrict__ Snap, const uint64_t* __restrict__ MaskSnap,
                        float* __restrict__ argout){
    __shared__ float t2s[CH_ * A_];
    __shared__ float wgs[33 * A_];
    __shared__ int   evc[CH_];
    int ch = blockIdx.x;             // 0..15
    int b  = blockIdx.y;             // 0..31
    int l  = threadIdx.x;            // 0..127
    int i0 = ch * CH_;
    for (int idx = l; idx < CH_ * A_; idx += 128)
        t2s[idx] = T2[((size_t)b * L_ + i0) * A_ + idx];
    for (int idx = l; idx < 33 * A_; idx += 128){
        int c = idx / A_, a = idx % A_;
        wgs[idx] = argw[(size_t)a * 545 + 512 + c];
    }
    if (l < CH_) evc[l] = Evcol[b * L_ + i0 + l];
    __syncthreads();
    float bg[A_];
    {
        const float* sp = Snap + (((size_t)b * NCH + ch) * L_ + l) * A_;
        #pragma unroll
        for (int a = 0; a < A_; a++) bg[a] = sp[a];
    }
    uint64_t mask = MaskSnap[((size_t)b * NCH + ch) * L_ + l];
    #pragma unroll 1
    for (int s = 0; s < CH_; s++){
        int i = i0 + s;
        const float* tr = t2s + s * A_;
        float lg[A_];
        #pragma unroll
        for (int a = 0; a < A_; a++) lg[a] = bg[a] + tr[a];
        float m1 = lg[1];
        #pragma unroll
        for (int a = 2; a < A_; a++) m1 = fmaxf(m1, lg[a]);
        bool apos = m1 > lg[0];
        float* op = argout + (((size_t)b * L_ + i) * L_ + l) * A_;
        #pragma unroll
        for (int q = 0; q < 9; q++){
            float4 v; v.x = lg[4*q]; v.y = lg[4*q+1]; v.z = lg[4*q+2]; v.w = lg[4*q+3];
            *(float4*)(op + 4 * q) = v;
        }
        int cc = evc[s];
        if (cc >= 0 && apos && !((mask >> cc) & 1ull)){
            mask |= 1ull << cc;
            const float* wc = wgs + cc * A_;
            #pragma unroll
            for (int a = 0; a < A_; a++) bg[a] += wc[a];
        }
    }
}

extern "C" void kernel_launch(void* const* d_in, const int* in_sizes, int n_in,
                              void* d_out, int out_size, void* d_ws, size_t ws_size,
                              hipStream_t stream){
    const int*   ids  = (const int*)  d_in[0];
    const float* emb  = (const float*)d_in[1];
    const float* wihf = (const float*)d_in[2];
    const float* whhf = (const float*)d_in[3];
    const float* bihf = (const float*)d_in[4];
    const float* bhhf = (const float*)d_in[5];
    const float* wihb = (const float*)d_in[6];
    const float* whhb = (const float*)d_in[7];
    const float* bihb = (const float*)d_in[8];
    const float* bhhb = (const float*)d_in[9];
    const float* evw  = (const float*)d_in[10];
    const float* evb  = (const float*)d_in[11];
    const float* argw = (const float*)d_in[12];
    const float* argb = (const float*)d_in[13];

    float* out0   = (float*)d_out;                 // [B,L,E] fp32
    float* argout = out0 + (size_t)M_ * E_;        // [B,L,L,A] fp32

    char* w = (char*)d_ws;                          // ~23.5 MB total
    float* WT    = (float*)w; w += (size_t)2 * DP_ * G_ * 4;   // 1.24 MB
    float* XW    = (float*)w; w += (size_t)2 * M_ * G_ * 4;    // 16.78 MB
    float* Hid   = (float*)w; w += (size_t)M_ * 256 * 4;       // 4.19 MB
    float* WcatT = (float*)w; w += (size_t)256 * NCP * 4;
    float* biasv = (float*)w; w += (size_t)NCP * 4;
    float* Base  = (float*)w; w += (size_t)M_ * A_ * 4;
    float* T2    = (float*)w; w += (size_t)M_ * A_ * 4;
    int*   Evcol = (int*)w;   w += (size_t)M_ * 4;

    // Scan snapshots alias the XW region (dead after k_lstm):
    // Snap 9.44 MB + MaskSnap 0.5 MB < 16.78 MB.
    float*    Snap     = XW;
    uint64_t* MaskSnap = (uint64_t*)(XW + (size_t)B_ * NCH * L_ * A_);

    k_prep1<<<dim3(DP_, 2), 512, 0, stream>>>(wihf, wihb, WT);
    k_prep2<<<256, 128, 0, stream>>>(evw, evb, argw, argb, WcatT, biasv);
    k_gemm1<<<dim3(M_ / 8, 2), 256, 0, stream>>>(ids, emb, WT, bihf, bhhf, bihb, bhhb, XW);
    k_lstm<<<64, 1024, 0, stream>>>(XW, whhf, whhb, Hid);
    k_heads2<<<M_, 128, 0, stream>>>(Hid, WcatT, biasv, out0, Base, T2, Evcol);
    k_scan1<<<B_, 128, 0, stream>>>(Base, T2, Evcol, argw, Snap, MaskSnap);
    k_scan2<<<dim3(NCH, B_), 128, 0, stream>>>(T2, Evcol, argw, Snap, MaskSnap, argout);
}

// Round 4
// 392.870 us; speedup vs baseline: 1.1764x; 1.1311x over previous
//
#include <hip/hip_runtime.h>
#include <hip/hip_bf16.h>
#include <stdint.h>

#define B_  32
#define L_  128
#define D_  300
#define DP_ 304
#define H_  128
#define G_  512
#define E_  34
#define A_  36
#define M_  4096   // B*L
#define NC_ 106    // 34 ev + 36 base + 36 t2
#define NCP 112    // padded col count
#define CH_ 8      // scan chunk length
#define NCH 16     // chunks per sequence
#define LCH 8      // lstm xw prefetch chunk length

__device__ __forceinline__ float sigf(float x){ return 1.0f / (1.0f + expf(-x)); }

// ---- P1: transpose W_ih into WT[d][k][n] (k-major, zero-padded k<304) ----
__global__ void k_prep1(const float* __restrict__ wihf, const float* __restrict__ wihb,
                        float* __restrict__ WT){
    int k = blockIdx.x;            // 0..303
    int d = blockIdx.y;            // 0..1
    int n = threadIdx.x;           // 0..511
    const float* w = d ? wihb : wihf;
    WT[((size_t)d * DP_ + k) * G_ + n] = (k < D_) ? w[(size_t)n * D_ + k] : 0.0f;
}

// ---- P2: pack head weights WcatT[k][n] (256 x NCP) + bias vector ----
__global__ void k_prep2(const float* __restrict__ evw, const float* __restrict__ evb,
                        const float* __restrict__ argw, const float* __restrict__ argb,
                        float* __restrict__ WcatT, float* __restrict__ biasv){
    int k = blockIdx.x;            // 0..255
    int n = threadIdx.x;           // 0..127
    if (n >= NCP) return;          // guard: block 128 wide, row 112
    float v = 0.0f;
    if (n < E_)       v = evw[(size_t)n * 256 + k];
    else if (n < 70)  v = argw[(size_t)(n - 34) * 545 + k];
    else if (n < NC_) v = argw[(size_t)(n - 70) * 545 + 256 + k];
    WcatT[(size_t)k * NCP + n] = v;
    if (k == 0){
        float bv = 0.0f;
        if (n < E_) bv = evb[n];
        else if (n < 70) bv = argb[n - 34];
        biasv[n] = bv;
    }
}

// ---- G1: XW[d][m][n] = emb[ids[m]][:] . w_ih_d[n][:] + b_ih[n] + b_hh[n] ----
// Round-8 retile (kept): 256 threads, 2 cols/thread, xs transposed to [k][r]:
// per-k LDS = 2x ds_read_b128 feeding 16 FMAs -> VALU-bound.
__launch_bounds__(256)
__global__ void k_gemm1(const int* __restrict__ ids, const float* __restrict__ emb,
                        const float* __restrict__ WT,
                        const float* __restrict__ bihf, const float* __restrict__ bhhf,
                        const float* __restrict__ bihb, const float* __restrict__ bhhb,
                        float* __restrict__ XW){
    __shared__ __align__(16) float xs[DP_][8];   // [k][r]
    int d  = blockIdx.y;
    int m0 = blockIdx.x * 8;
    int tid = threadIdx.x;         // 0..255
    for (int idx = tid; idx < 8 * DP_; idx += 256){
        int r = idx / DP_, k = idx % DP_;
        int id = ids[m0 + r];
        xs[k][r] = (k < D_) ? emb[(size_t)id * D_ + k] : 0.0f;
    }
    __syncthreads();
    int n0 = tid, n1 = tid + 256;
    const float* w0 = WT + (size_t)d * DP_ * G_ + n0;
    const float* w1 = WT + (size_t)d * DP_ * G_ + n1;
    const float4* xs4 = (const float4*)xs;
    float acc0[8] = {}, acc1[8] = {};
    #pragma unroll 2
    for (int k = 0; k < D_; k++){
        float wv0 = w0[(size_t)k * G_];
        float wv1 = w1[(size_t)k * G_];
        float4 xA = xs4[k * 2], xB = xs4[k * 2 + 1];
        acc0[0] += xA.x * wv0; acc0[1] += xA.y * wv0;
        acc0[2] += xA.z * wv0; acc0[3] += xA.w * wv0;
        acc0[4] += xB.x * wv0; acc0[5] += xB.y * wv0;
        acc0[6] += xB.z * wv0; acc0[7] += xB.w * wv0;
        acc1[0] += xA.x * wv1; acc1[1] += xA.y * wv1;
        acc1[2] += xA.z * wv1; acc1[3] += xA.w * wv1;
        acc1[4] += xB.x * wv1; acc1[5] += xB.y * wv1;
        acc1[6] += xB.z * wv1; acc1[7] += xB.w * wv1;
    }
    float bias0 = d ? (bihb[n0] + bhhb[n0]) : (bihf[n0] + bhhf[n0]);
    float bias1 = d ? (bihb[n1] + bhhb[n1]) : (bihf[n1] + bhhf[n1]);
    for (int r = 0; r < 8; r++){
        XW[((size_t)d * M_ + m0 + r) * G_ + n0] = acc0[r] + bias0;
        XW[((size_t)d * M_ + m0 + r) * G_ + n1] = acc1[r] + bias1;
    }
}

// ---- K3: LSTM recurrence. 64 blocks = (dir,b); 1024 threads, 2-way K-split.
// Round-10 fixes over round-9 (which hit 176us):
//  (a) launch_bounds(1024,2): round-9's (1024,4) capped regs at 128, forcing
//      the 64-reg weight array into AGPRs (VGPR_Count=52 => 52+64 split) and
//      paying v_accvgpr moves every step. Cap 256 lets ~116 regs stay arch.
//      Actual occupancy is grid-limited (64 blocks/256 CUs) - unchanged.
//  (b) SQ_LDS_BANK_CONFLICT was 2^23: half-0 reads hbuf[4q] (bank 4q),
//      half-1 reads hbuf[64+4q] (bank 4q too) -> 2-addr same-bank on every
//      b128. Fix: TWO copies of h with +4-float bank phase (hball[0],
//      hball[132]); half-1 reads its k-slice from copy B -> disjoint banks.
//      Same values, same order => bit-identical.
//  (c) phase B owners = tid<128 (2 full waves, 64/64 lanes active).
#define STEP(S_, XWV)                                                           \
{                                                                               \
    float a0=0.f,a1=0.f,a2=0.f,a3=0.f;                                          \
    _Pragma("unroll")                                                           \
    for (int q = 0; q < 16; q++){                                               \
        float4 hv = hc[q];                                                      \
        a0 += wv[q].x * hv.x; a1 += wv[q].y * hv.y;                             \
        a2 += wv[q].z * hv.z; a3 += wv[q].w * hv.w;                             \
    }                                                                           \
    float part  = (a0 + a1) + (a2 + a3);                                        \
    float other = __shfl_xor(part, 1);                                          \
    if (half == 0){                                                             \
        float z = ((XWV) + part) + other;                                       \
        zbuf[row] = gate_g ? tanhf(z) : sigf(z);                                \
    }                                                                           \
    __syncthreads();                                                            \
    if (pb){                                                                    \
        float I = zbuf[tid], F = zbuf[H_ + tid];                                \
        float G = zbuf[2*H_ + tid], O = zbuf[3*H_ + tid];                       \
        c = F * c + I * G;                                                      \
        float h = O * tanhf(c);                                                 \
        hball[tid] = h; hball[132 + tid] = h;                                   \
        hist[(size_t)(S_) * H_ + tid] = h;                                      \
    }                                                                           \
    __syncthreads();                                                            \
}

__launch_bounds__(1024, 2)
__global__ void k_lstm(const float* __restrict__ XW, const float* __restrict__ whhf,
                       const float* __restrict__ whhb, float* __restrict__ Hid){
    __shared__ __align__(16) float hball[260];      // h copy A @0, copy B @132 (+4 bank phase)
    __shared__ float zbuf[G_];                      // activated gate values
    __shared__ __align__(16) float hist[L_ * H_];   // 64 KB full h history
    int bid = blockIdx.x;
    int d = bid >> 5, b = bid & 31;
    int tid = threadIdx.x;         // 0..1023
    int row = tid >> 1;            // 0..511  (z-row)
    int half = tid & 1;            // K-half: 0 -> k 0..63, 1 -> k 64..127
    bool gate_g = (row >= 256) && (row < 384);   // wave-uniform (32 rows/wave)
    bool pb = (tid < H_);                        // phase-B owner for n=tid
    const float* whh = d ? whhb : whhf;
    const float4* wr = (const float4*)(whh + (size_t)row * H_ + half * 64);
    float4 wv[16];
    #pragma unroll
    for (int q = 0; q < 16; q++) wv[q] = wr[q];
    // half 0 reads h[0..63] from copy A (banks 4q..); half 1 reads h[64..127]
    // from copy B base 132+64=196 floats (banks 4q+4..) -> no shared banks.
    const float4* hc = (const float4*)(hball + (half ? 196 : 0));
    float c = 0.0f;
    if (tid < H_){ hball[tid] = 0.0f; hball[132 + tid] = 0.0f; }
    __syncthreads();
    const float* xwn = XW + ((size_t)d * M_ + (size_t)b * L_) * G_ + row;
    #pragma unroll 1
    for (int ch = 0; ch < L_ / LCH; ch++){
        float xr[LCH];
        #pragma unroll
        for (int j = 0; j < LCH; j++){
            int s_ = ch * LCH + j;
            int t_ = d ? (L_ - 1 - s_) : s_;
            xr[j] = xwn[(size_t)t_ * G_];   // lane pairs load same addr (ok)
        }
        #pragma unroll
        for (int j = 0; j < LCH; j++){
            STEP(ch * LCH + j, xr[j])
        }
    }
    // bulk flush: 128 steps x 128 h = 4096 float4, 4 per thread
    const float4* hist4 = (const float4*)hist;
    #pragma unroll
    for (int q = 0; q < 4; q++){
        int idx = tid + q * 1024;
        int sl = idx >> 5, n4 = idx & 31;
        int t_ = d ? (L_ - 1 - sl) : sl;
        *(float4*)(Hid + ((size_t)b * L_ + t_) * 256 + d * H_ + n4 * 4) =
            hist4[(size_t)sl * 32 + n4];
    }
}

// ---- K4: heads. One block per m. cols: 0..33 ev, 34..69 base, 70..105 t2. ----
__launch_bounds__(128)
__global__ void k_heads2(const float* __restrict__ Hid, const float* __restrict__ WcatT,
                         const float* __restrict__ biasv,
                         float* __restrict__ out0, float* __restrict__ Base,
                         float* __restrict__ T2, int* __restrict__ Evcol){
    __shared__ float hs[256];
    __shared__ float evl[E_];
    int m = blockIdx.x;
    int tid = threadIdx.x;         // 0..127
    hs[tid]       = Hid[(size_t)m * 256 + tid];
    hs[tid + 128] = Hid[(size_t)m * 256 + 128 + tid];
    __syncthreads();
    float acc = 0.0f;
    if (tid < NC_){
        const float* wc = WcatT + tid;
        for (int k = 0; k < 256; k++) acc += hs[k] * wc[(size_t)k * NCP];
        acc += biasv[tid];
    }
    if (tid < E_){
        out0[(size_t)m * E_ + tid] = acc;   // fp32 output
        evl[tid] = acc;
    } else if (tid < 70){
        Base[(size_t)m * A_ + (tid - 34)] = acc;
    } else if (tid < NC_){
        T2[(size_t)m * A_ + (tid - 70)] = acc;
    }
    __syncthreads();
    if (tid == 0){                 // first-max argmax over E=34
        float best = evl[0]; int bi = 0;
        for (int e = 1; e < E_; e++){
            float v = evl[e];
            if (v > best){ best = v; bi = e; }
        }
        Evcol[m] = bi - 1;         // -1 => ev_pred==0 (no g update)
    }
}

// ---- K5a: serial state propagation only. Snapshots (bg, mask) every CH_ steps.
// No argout stores here — that's phase 2's job.
__launch_bounds__(128)
__global__ void k_scan1(const float* __restrict__ Base, const float* __restrict__ T2,
                        const int* __restrict__ Evcol, const float* __restrict__ argw,
                        float* __restrict__ Snap, uint64_t* __restrict__ MaskSnap){
    __shared__ float t2s[L_ * A_];
    __shared__ float wgs[33 * A_];
    __shared__ int   evc[L_];
    int b = blockIdx.x;
    int l = threadIdx.x;             // 0..127
    for (int idx = l; idx < L_ * A_; idx += 128)
        t2s[idx] = T2[(size_t)b * L_ * A_ + idx];
    for (int idx = l; idx < 33 * A_; idx += 128){
        int c = idx / A_, a = idx % A_;
        wgs[idx] = argw[(size_t)a * 545 + 512 + c];
    }
    evc[l] = Evcol[b * L_ + l];
    __syncthreads();
    float bg[A_];
    {
        const float* bp = Base + ((size_t)b * L_ + l) * A_;
        #pragma unroll
        for (int a = 0; a < A_; a++) bg[a] = bp[a];
    }
    uint64_t mask = 0;
    #pragma unroll 1
    for (int i = 0; i < L_; i++){
        if ((i & (CH_ - 1)) == 0){
            int ch = i >> 3;
            float* sp = Snap + (((size_t)b * NCH + ch) * L_ + l) * A_;
            #pragma unroll
            for (int a = 0; a < A_; a++) sp[a] = bg[a];
            MaskSnap[((size_t)b * NCH + ch) * L_ + l] = mask;
        }
        const float* tr = t2s + i * A_;
        float lg0 = bg[0] + tr[0];
        float m1  = bg[1] + tr[1];
        #pragma unroll
        for (int a = 2; a < A_; a++) m1 = fmaxf(m1, bg[a] + tr[a]);
        bool apos = m1 > lg0;
        int cc = evc[i];
        if (cc >= 0 && apos && !((mask >> cc) & 1ull)){
            mask |= 1ull << cc;
            const float* wc = wgs + cc * A_;
            #pragma unroll
            for (int a = 0; a < A_; a++) bg[a] += wc[a];
        }
    }
}

// ---- K5b: parallel replay of CH_-step chunks from snapshots; does all stores.
// Bit-exact same ops as k_scan1 => identical decisions, exact state continuity.
__launch_bounds__(128)
__global__ void k_scan2(const float* __restrict__ T2, const int* __restrict__ Evcol,
                        const float* __restrict__ argw,
                        const float* __restrict__ Snap, const uint64_t* __restrict__ MaskSnap,
                        float* __restrict__ argout){
    __shared__ float t2s[CH_ * A_];
    __shared__ float wgs[33 * A_];
    __shared__ int   evc[CH_];
    int ch = blockIdx.x;             // 0..15
    int b  = blockIdx.y;             // 0..31
    int l  = threadIdx.x;            // 0..127
    int i0 = ch * CH_;
    for (int idx = l; idx < CH_ * A_; idx += 128)
        t2s[idx] = T2[((size_t)b * L_ + i0) * A_ + idx];
    for (int idx = l; idx < 33 * A_; idx += 128){
        int c = idx / A_, a = idx % A_;
        wgs[idx] = argw[(size_t)a * 545 + 512 + c];
    }
    if (l < CH_) evc[l] = Evcol[b * L_ + i0 + l];
    __syncthreads();
    float bg[A_];
    {
        const float* sp = Snap + (((size_t)b * NCH + ch) * L_ + l) * A_;
        #pragma unroll
        for (int a = 0; a < A_; a++) bg[a] = sp[a];
    }
    uint64_t mask = MaskSnap[((size_t)b * NCH + ch) * L_ + l];
    #pragma unroll 1
    for (int s = 0; s < CH_; s++){
        int i = i0 + s;
        const float* tr = t2s + s * A_;
        float lg[A_];
        #pragma unroll
        for (int a = 0; a < A_; a++) lg[a] = bg[a] + tr[a];
        float m1 = lg[1];
        #pragma unroll
        for (int a = 2; a < A_; a++) m1 = fmaxf(m1, lg[a]);
        bool apos = m1 > lg[0];
        float* op = argout + (((size_t)b * L_ + i) * L_ + l) * A_;
        #pragma unroll
        for (int q = 0; q < 9; q++){
            float4 v; v.x = lg[4*q]; v.y = lg[4*q+1]; v.z = lg[4*q+2]; v.w = lg[4*q+3];
            *(float4*)(op + 4 * q) = v;
        }
        int cc = evc[s];
        if (cc >= 0 && apos && !((mask >> cc) & 1ull)){
            mask |= 1ull << cc;
            const float* wc = wgs + cc * A_;
            #pragma unroll
            for (int a = 0; a < A_; a++) bg[a] += wc[a];
        }
    }
}

extern "C" void kernel_launch(void* const* d_in, const int* in_sizes, int n_in,
                              void* d_out, int out_size, void* d_ws, size_t ws_size,
                              hipStream_t stream){
    const int*   ids  = (const int*)  d_in[0];
    const float* emb  = (const float*)d_in[1];
    const float* wihf = (const float*)d_in[2];
    const float* whhf = (const float*)d_in[3];
    const float* bihf = (const float*)d_in[4];
    const float* bhhf = (const float*)d_in[5];
    const float* wihb = (const float*)d_in[6];
    const float* whhb = (const float*)d_in[7];
    const float* bihb = (const float*)d_in[8];
    const float* bhhb = (const float*)d_in[9];
    const float* evw  = (const float*)d_in[10];
    const float* evb  = (const float*)d_in[11];
    const float* argw = (const float*)d_in[12];
    const float* argb = (const float*)d_in[13];

    float* out0   = (float*)d_out;                 // [B,L,E] fp32
    float* argout = out0 + (size_t)M_ * E_;        // [B,L,L,A] fp32

    char* w = (char*)d_ws;                          // ~23.5 MB total
    float* WT    = (float*)w; w += (size_t)2 * DP_ * G_ * 4;   // 1.24 MB
    float* XW    = (float*)w; w += (size_t)2 * M_ * G_ * 4;    // 16.78 MB
    float* Hid   = (float*)w; w += (size_t)M_ * 256 * 4;       // 4.19 MB
    float* WcatT = (float*)w; w += (size_t)256 * NCP * 4;
    float* biasv = (float*)w; w += (size_t)NCP * 4;
    float* Base  = (float*)w; w += (size_t)M_ * A_ * 4;
    float* T2    = (float*)w; w += (size_t)M_ * A_ * 4;
    int*   Evcol = (int*)w;   w += (size_t)M_ * 4;

    // Scan snapshots alias the XW region (dead after k_lstm):
    // Snap 9.44 MB + MaskSnap 0.5 MB < 16.78 MB.
    float*    Snap     = XW;
    uint64_t* MaskSnap = (uint64_t*)(XW + (size_t)B_ * NCH * L_ * A_);

    k_prep1<<<dim3(DP_, 2), 512, 0, stream>>>(wihf, wihb, WT);
    k_prep2<<<256, 128, 0, stream>>>(evw, evb, argw, argb, WcatT, biasv);
    k_gemm1<<<dim3(M_ / 8, 2), 256, 0, stream>>>(ids, emb, WT, bihf, bhhf, bihb, bhhb, XW);
    k_lstm<<<64, 1024, 0, stream>>>(XW, whhf, whhb, Hid);
    k_heads2<<<M_, 128, 0, stream>>>(Hid, WcatT, biasv, out0, Base, T2, Evcol);
    k_scan1<<<B_, 128, 0, stream>>>(Base, T2, Evcol, argw, Snap, MaskSnap);
    k_scan2<<<dim3(NCH, B_), 128, 0, stream>>>(T2, Evcol, argw, Snap, MaskSnap, argout);
}

// Round 5
// 392.374 us; speedup vs baseline: 1.1778x; 1.0013x over previous
//
#include <hip/hip_runtime.h>
#include <hip/hip_bf16.h>
#include <stdint.h>

#define B_  32
#define L_  128
#define D_  300
#define DP_ 304
#define H_  128
#define G_  512
#define E_  34
#define A_  36
#define M_  4096   // B*L
#define NC_ 106    // 34 ev + 36 base + 36 t2
#define NCP 112    // padded col count
#define CH_ 8      // scan chunk length
#define NCH 16     // chunks per sequence
#define LCH 8      // lstm xw prefetch chunk length
#define NCHK (L_ / LCH)

__device__ __forceinline__ float sigf(float x){ return 1.0f / (1.0f + expf(-x)); }

// ---- P1: transpose W_ih into WT[d][k][n] (k-major, zero-padded k<304) ----
__global__ void k_prep1(const float* __restrict__ wihf, const float* __restrict__ wihb,
                        float* __restrict__ WT){
    int k = blockIdx.x;            // 0..303
    int d = blockIdx.y;            // 0..1
    int n = threadIdx.x;           // 0..511
    const float* w = d ? wihb : wihf;
    WT[((size_t)d * DP_ + k) * G_ + n] = (k < D_) ? w[(size_t)n * D_ + k] : 0.0f;
}

// ---- P2: pack head weights WcatT[k][n] (256 x NCP) + bias vector ----
__global__ void k_prep2(const float* __restrict__ evw, const float* __restrict__ evb,
                        const float* __restrict__ argw, const float* __restrict__ argb,
                        float* __restrict__ WcatT, float* __restrict__ biasv){
    int k = blockIdx.x;            // 0..255
    int n = threadIdx.x;           // 0..127
    if (n >= NCP) return;          // guard: block 128 wide, row 112
    float v = 0.0f;
    if (n < E_)       v = evw[(size_t)n * 256 + k];
    else if (n < 70)  v = argw[(size_t)(n - 34) * 545 + k];
    else if (n < NC_) v = argw[(size_t)(n - 70) * 545 + 256 + k];
    WcatT[(size_t)k * NCP + n] = v;
    if (k == 0){
        float bv = 0.0f;
        if (n < E_) bv = evb[n];
        else if (n < 70) bv = argb[n - 34];
        biasv[n] = bv;
    }
}

// ---- G1: XW[d][m][n] = emb[ids[m]][:] . w_ih_d[n][:] + b_ih[n] + b_hh[n] ----
// Round-8 retile (kept): 256 threads, 2 cols/thread, xs transposed to [k][r]:
// per-k LDS = 2x ds_read_b128 feeding 16 FMAs -> VALU-bound.
__launch_bounds__(256)
__global__ void k_gemm1(const int* __restrict__ ids, const float* __restrict__ emb,
                        const float* __restrict__ WT,
                        const float* __restrict__ bihf, const float* __restrict__ bhhf,
                        const float* __restrict__ bihb, const float* __restrict__ bhhb,
                        float* __restrict__ XW){
    __shared__ __align__(16) float xs[DP_][8];   // [k][r]
    int d  = blockIdx.y;
    int m0 = blockIdx.x * 8;
    int tid = threadIdx.x;         // 0..255
    for (int idx = tid; idx < 8 * DP_; idx += 256){
        int r = idx / DP_, k = idx % DP_;
        int id = ids[m0 + r];
        xs[k][r] = (k < D_) ? emb[(size_t)id * D_ + k] : 0.0f;
    }
    __syncthreads();
    int n0 = tid, n1 = tid + 256;
    const float* w0 = WT + (size_t)d * DP_ * G_ + n0;
    const float* w1 = WT + (size_t)d * DP_ * G_ + n1;
    const float4* xs4 = (const float4*)xs;
    float acc0[8] = {}, acc1[8] = {};
    #pragma unroll 2
    for (int k = 0; k < D_; k++){
        float wv0 = w0[(size_t)k * G_];
        float wv1 = w1[(size_t)k * G_];
        float4 xA = xs4[k * 2], xB = xs4[k * 2 + 1];
        acc0[0] += xA.x * wv0; acc0[1] += xA.y * wv0;
        acc0[2] += xA.z * wv0; acc0[3] += xA.w * wv0;
        acc0[4] += xB.x * wv0; acc0[5] += xB.y * wv0;
        acc0[6] += xB.z * wv0; acc0[7] += xB.w * wv0;
        acc1[0] += xA.x * wv1; acc1[1] += xA.y * wv1;
        acc1[2] += xA.z * wv1; acc1[3] += xA.w * wv1;
        acc1[4] += xB.x * wv1; acc1[5] += xB.y * wv1;
        acc1[6] += xB.z * wv1; acc1[7] += xB.w * wv1;
    }
    float bias0 = d ? (bihb[n0] + bhhb[n0]) : (bihf[n0] + bhhf[n0]);
    float bias1 = d ? (bihb[n1] + bhhb[n1]) : (bihf[n1] + bhhf[n1]);
    for (int r = 0; r < 8; r++){
        XW[((size_t)d * M_ + m0 + r) * G_ + n0] = acc0[r] + bias0;
        XW[((size_t)d * M_ + m0 + r) * G_ + n1] = acc1[r] + bias1;
    }
}

// ---- K3: LSTM recurrence. 64 blocks = (dir,b); 512 threads, full-row.
// Round-11 restructure: ONE barrier per step, wave-local phase B.
//  * Row remap: wave w, lane l owns z-row (l>>4)*128 + w*16 + (l&15), so the
//    i,f,g,o values of hidden unit n = w*16+(l&15) all live in ONE wave.
//    Gate gather = 3x __shfl_xor(v, 16/32/48) - no zbuf, no 2nd barrier,
//    no LDS read latency in the c-update path.
//  * Phase B distributed: lanes 0..15 of EVERY wave do their 16 units' c/h
//    update in parallel (was: 2 waves busy, 14 idle).
//  * h double-buffered in LDS (hb0/hb1, parity static under unroll) so a
//    single __syncthreads per step is race-free.
//  * xw prefetch double-buffered one chunk ahead (xA/xB, static indexing).
// Numerics: identical z summation (same 4-chain full-row order as round-7),
// same gate formulas -> bit-identical to previous rounds.
#define PF(XR, CHI)                                                             \
{                                                                               \
    if ((CHI) < NCHK){                                                          \
        _Pragma("unroll")                                                       \
        for (int j = 0; j < LCH; j++){                                          \
            int s_ = (CHI) * LCH + j;                                           \
            int t_ = d ? (L_ - 1 - s_) : s_;                                    \
            XR[j] = xwn[(size_t)t_ * G_];                                       \
        }                                                                       \
    }                                                                           \
}

#define STEP8(XR, CHI)                                                          \
{                                                                               \
    _Pragma("unroll")                                                           \
    for (int j = 0; j < LCH; j++){                                              \
        int s_ = (CHI) * LCH + j;                                               \
        const float4* hc = (const float4*)((j & 1) ? hb1 : hb0);                \
        float a0=0.f,a1=0.f,a2=0.f,a3=0.f;                                      \
        _Pragma("unroll")                                                       \
        for (int q = 0; q < 32; q++){                                           \
            float4 hv = hc[q];                                                  \
            a0 += wv[q].x * hv.x; a1 += wv[q].y * hv.y;                         \
            a2 += wv[q].z * hv.z; a3 += wv[q].w * hv.w;                         \
        }                                                                       \
        float z = XR[j] + ((a0 + a1) + (a2 + a3));                              \
        float v = (gi == 2) ? tanhf(z) : sigf(z);                               \
        float Fv = __shfl_xor(v, 16);                                           \
        float Gv = __shfl_xor(v, 32);                                           \
        float Ov = __shfl_xor(v, 48);                                           \
        if (lane < 16){                                                         \
            c = Fv * c + v * Gv;                                                \
            float h = Ov * tanhf(c);                                            \
            float* hw = (j & 1) ? hb0 : hb1;                                    \
            hw[n16] = h;                                                        \
            hist[(size_t)(s_) * H_ + n16] = h;                                  \
        }                                                                       \
        __syncthreads();                                                        \
    }                                                                           \
}

__launch_bounds__(512, 2)
__global__ void k_lstm(const float* __restrict__ XW, const float* __restrict__ whhf,
                       const float* __restrict__ whhb, float* __restrict__ Hid){
    __shared__ __align__(16) float hb0[H_];
    __shared__ __align__(16) float hb1[H_];
    __shared__ __align__(16) float hist[L_ * H_];   // 64 KB full h history
    int bid = blockIdx.x;
    int d = bid >> 5, b = bid & 31;
    int tid = threadIdx.x;         // 0..511
    int wvi  = tid >> 6;           // wave 0..7
    int lane = tid & 63;
    int n16  = wvi * 16 + (lane & 15);   // hidden unit owned (lanes 0..15)
    int gi   = lane >> 4;                // 0=i 1=f 2=g 3=o
    int row  = gi * H_ + n16;            // z-row in [0,512)
    const float* whh = d ? whhb : whhf;
    const float4* wr = (const float4*)(whh + (size_t)row * H_);
    float4 wv[32];
    #pragma unroll
    for (int q = 0; q < 32; q++) wv[q] = wr[q];
    float c = 0.0f;
    if (tid < H_) hb0[tid] = 0.0f;
    __syncthreads();
    const float* xwn = XW + ((size_t)d * M_ + (size_t)b * L_) * G_ + row;
    float xA[LCH], xB[LCH];
    PF(xA, 0)
    #pragma unroll 1
    for (int cp = 0; cp < NCHK / 2; cp++){
        PF(xB, 2 * cp + 1)
        STEP8(xA, 2 * cp)
        PF(xA, 2 * cp + 2)
        STEP8(xB, 2 * cp + 1)
    }
    // bulk flush: 128 steps x 128 h = 4096 float4, 8 per thread
    const float4* hist4 = (const float4*)hist;
    #pragma unroll
    for (int q = 0; q < 8; q++){
        int idx = tid + q * 512;
        int sl = idx >> 5, n4 = idx & 31;
        int t_ = d ? (L_ - 1 - sl) : sl;
        *(float4*)(Hid + ((size_t)b * L_ + t_) * 256 + d * H_ + n4 * 4) =
            hist4[(size_t)sl * 32 + n4];
    }
}

// ---- K4: heads. One block per m. cols: 0..33 ev, 34..69 base, 70..105 t2. ----
__launch_bounds__(128)
__global__ void k_heads2(const float* __restrict__ Hid, const float* __restrict__ WcatT,
                         const float* __restrict__ biasv,
                         float* __restrict__ out0, float* __restrict__ Base,
                         float* __restrict__ T2, int* __restrict__ Evcol){
    __shared__ float hs[256];
    __shared__ float evl[E_];
    int m = blockIdx.x;
    int tid = threadIdx.x;         // 0..127
    hs[tid]       = Hid[(size_t)m * 256 + tid];
    hs[tid + 128] = Hid[(size_t)m * 256 + 128 + tid];
    __syncthreads();
    float acc = 0.0f;
    if (tid < NC_){
        const float* wc = WcatT + tid;
        for (int k = 0; k < 256; k++) acc += hs[k] * wc[(size_t)k * NCP];
        acc += biasv[tid];
    }
    if (tid < E_){
        out0[(size_t)m * E_ + tid] = acc;   // fp32 output
        evl[tid] = acc;
    } else if (tid < 70){
        Base[(size_t)m * A_ + (tid - 34)] = acc;
    } else if (tid < NC_){
        T2[(size_t)m * A_ + (tid - 70)] = acc;
    }
    __syncthreads();
    if (tid == 0){                 // first-max argmax over E=34
        float best = evl[0]; int bi = 0;
        for (int e = 1; e < E_; e++){
            float v = evl[e];
            if (v > best){ best = v; bi = e; }
        }
        Evcol[m] = bi - 1;         // -1 => ev_pred==0 (no g update)
    }
}

// ---- K5a: serial state propagation only. Snapshots (bg, mask) every CH_ steps.
// No argout stores here — that's phase 2's job.
__launch_bounds__(128)
__global__ void k_scan1(const float* __restrict__ Base, const float* __restrict__ T2,
                        const int* __restrict__ Evcol, const float* __restrict__ argw,
                        float* __restrict__ Snap, uint64_t* __restrict__ MaskSnap){
    __shared__ float t2s[L_ * A_];
    __shared__ float wgs[33 * A_];
    __shared__ int   evc[L_];
    int b = blockIdx.x;
    int l = threadIdx.x;             // 0..127
    for (int idx = l; idx < L_ * A_; idx += 128)
        t2s[idx] = T2[(size_t)b * L_ * A_ + idx];
    for (int idx = l; idx < 33 * A_; idx += 128){
        int c = idx / A_, a = idx % A_;
        wgs[idx] = argw[(size_t)a * 545 + 512 + c];
    }
    evc[l] = Evcol[b * L_ + l];
    __syncthreads();
    float bg[A_];
    {
        const float* bp = Base + ((size_t)b * L_ + l) * A_;
        #pragma unroll
        for (int a = 0; a < A_; a++) bg[a] = bp[a];
    }
    uint64_t mask = 0;
    #pragma unroll 1
    for (int i = 0; i < L_; i++){
        if ((i & (CH_ - 1)) == 0){
            int ch = i >> 3;
            float* sp = Snap + (((size_t)b * NCH + ch) * L_ + l) * A_;
            #pragma unroll
            for (int a = 0; a < A_; a++) sp[a] = bg[a];
            MaskSnap[((size_t)b * NCH + ch) * L_ + l] = mask;
        }
        const float* tr = t2s + i * A_;
        float lg0 = bg[0] + tr[0];
        float m1  = bg[1] + tr[1];
        #pragma unroll
        for (int a = 2; a < A_; a++) m1 = fmaxf(m1, bg[a] + tr[a]);
        bool apos = m1 > lg0;
        int cc = evc[i];
        if (cc >= 0 && apos && !((mask >> cc) & 1ull)){
            mask |= 1ull << cc;
            const float* wc = wgs + cc * A_;
            #pragma unroll
            for (int a = 0; a < A_; a++) bg[a] += wc[a];
        }
    }
}

// ---- K5b: parallel replay of CH_-step chunks from snapshots; does all stores.
// Bit-exact same ops as k_scan1 => identical decisions, exact state continuity.
__launch_bounds__(128)
__global__ void k_scan2(const float* __restrict__ T2, const int* __restrict__ Evcol,
                        const float* __restrict__ argw,
                        const float* __restrict__ Snap, const uint64_t* __restrict__ MaskSnap,
                        float* __restrict__ argout){
    __shared__ float t2s[CH_ * A_];
    __shared__ float wgs[33 * A_];
    __shared__ int   evc[CH_];
    int ch = blockIdx.x;             // 0..15
    int b  = blockIdx.y;             // 0..31
    int l  = threadIdx.x;            // 0..127
    int i0 = ch * CH_;
    for (int idx = l; idx < CH_ * A_; idx += 128)
        t2s[idx] = T2[((size_t)b * L_ + i0) * A_ + idx];
    for (int idx = l; idx < 33 * A_; idx += 128){
        int c = idx / A_, a = idx % A_;
        wgs[idx] = argw[(size_t)a * 545 + 512 + c];
    }
    if (l < CH_) evc[l] = Evcol[b * L_ + i0 + l];
    __syncthreads();
    float bg[A_];
    {
        const float* sp = Snap + (((size_t)b * NCH + ch) * L_ + l) * A_;
        #pragma unroll
        for (int a = 0; a < A_; a++) bg[a] = sp[a];
    }
    uint64_t mask = MaskSnap[((size_t)b * NCH + ch) * L_ + l];
    #pragma unroll 1
    for (int s = 0; s < CH_; s++){
        int i = i0 + s;
        const float* tr = t2s + s * A_;
        float lg[A_];
        #pragma unroll
        for (int a = 0; a < A_; a++) lg[a] = bg[a] + tr[a];
        float m1 = lg[1];
        #pragma unroll
        for (int a = 2; a < A_; a++) m1 = fmaxf(m1, lg[a]);
        bool apos = m1 > lg[0];
        float* op = argout + (((size_t)b * L_ + i) * L_ + l) * A_;
        #pragma unroll
        for (int q = 0; q < 9; q++){
            float4 v; v.x = lg[4*q]; v.y = lg[4*q+1]; v.z = lg[4*q+2]; v.w = lg[4*q+3];
            *(float4*)(op + 4 * q) = v;
        }
        int cc = evc[s];
        if (cc >= 0 && apos && !((mask >> cc) & 1ull)){
            mask |= 1ull << cc;
            const float* wc = wgs + cc * A_;
            #pragma unroll
            for (int a = 0; a < A_; a++) bg[a] += wc[a];
        }
    }
}

extern "C" void kernel_launch(void* const* d_in, const int* in_sizes, int n_in,
                              void* d_out, int out_size, void* d_ws, size_t ws_size,
                              hipStream_t stream){
    const int*   ids  = (const int*)  d_in[0];
    const float* emb  = (const float*)d_in[1];
    const float* wihf = (const float*)d_in[2];
    const float* whhf = (const float*)d_in[3];
    const float* bihf = (const float*)d_in[4];
    const float* bhhf = (const float*)d_in[5];
    const float* wihb = (const float*)d_in[6];
    const float* whhb = (const float*)d_in[7];
    const float* bihb = (const float*)d_in[8];
    const float* bhhb = (const float*)d_in[9];
    const float* evw  = (const float*)d_in[10];
    const float* evb  = (const float*)d_in[11];
    const float* argw = (const float*)d_in[12];
    const float* argb = (const float*)d_in[13];

    float* out0   = (float*)d_out;                 // [B,L,E] fp32
    float* argout = out0 + (size_t)M_ * E_;        // [B,L,L,A] fp32

    char* w = (char*)d_ws;                          // ~23.5 MB total
    float* WT    = (float*)w; w += (size_t)2 * DP_ * G_ * 4;   // 1.24 MB
    float* XW    = (float*)w; w += (size_t)2 * M_ * G_ * 4;    // 16.78 MB
    float* Hid   = (float*)w; w += (size_t)M_ * 256 * 4;       // 4.19 MB
    float* WcatT = (float*)w; w += (size_t)256 * NCP * 4;
    float* biasv = (float*)w; w += (size_t)NCP * 4;
    float* Base  = (float*)w; w += (size_t)M_ * A_ * 4;
    float* T2    = (float*)w; w += (size_t)M_ * A_ * 4;
    int*   Evcol = (int*)w;   w += (size_t)M_ * 4;

    // Scan snapshots alias the XW region (dead after k_lstm):
    // Snap 9.44 MB + MaskSnap 0.5 MB < 16.78 MB.
    float*    Snap     = XW;
    uint64_t* MaskSnap = (uint64_t*)(XW + (size_t)B_ * NCH * L_ * A_);

    k_prep1<<<dim3(DP_, 2), 512, 0, stream>>>(wihf, wihb, WT);
    k_prep2<<<256, 128, 0, stream>>>(evw, evb, argw, argb, WcatT, biasv);
    k_gemm1<<<dim3(M_ / 8, 2), 256, 0, stream>>>(ids, emb, WT, bihf, bhhf, bihb, bhhb, XW);
    k_lstm<<<64, 512, 0, stream>>>(XW, whhf, whhb, Hid);
    k_heads2<<<M_, 128, 0, stream>>>(Hid, WcatT, biasv, out0, Base, T2, Evcol);
    k_scan1<<<B_, 128, 0, stream>>>(Base, T2, Evcol, argw, Snap, MaskSnap);
    k_scan2<<<dim3(NCH, B_), 128, 0, stream>>>(T2, Evcol, argw, Snap, MaskSnap, argout);
}

// Round 6
// 388.757 us; speedup vs baseline: 1.1888x; 1.0093x over previous
//
#include <hip/hip_runtime.h>
#include <hip/hip_bf16.h>
#include <stdint.h>

#define B_  32
#define L_  128
#define D_  300
#define DP_ 304
#define H_  128
#define G_  512
#define E_  34
#define A_  36
#define M_  4096   // B*L
#define NC_ 106    // 34 ev + 36 base + 36 t2
#define NCP 112    // padded col count
#define CH_ 8      // scan chunk length
#define NCH 16     // chunks per sequence
#define LCH 8      // lstm xw prefetch chunk length
#define NCHK (L_ / LCH)
#define BM_ 16     // gemm1 rows per block

typedef float f2 __attribute__((ext_vector_type(2)));

__device__ __forceinline__ float sigf(float x){ return 1.0f / (1.0f + expf(-x)); }

// ---- P1: transpose W_ih into WT[d][k][n] (k-major, zero-padded k<304) ----
__global__ void k_prep1(const float* __restrict__ wihf, const float* __restrict__ wihb,
                        float* __restrict__ WT){
    int k = blockIdx.x;            // 0..303
    int d = blockIdx.y;            // 0..1
    int n = threadIdx.x;           // 0..511
    const float* w = d ? wihb : wihf;
    WT[((size_t)d * DP_ + k) * G_ + n] = (k < D_) ? w[(size_t)n * D_ + k] : 0.0f;
}

// ---- P2: pack head weights WcatT[k][n] (256 x NCP) + bias vector ----
__global__ void k_prep2(const float* __restrict__ evw, const float* __restrict__ evb,
                        const float* __restrict__ argw, const float* __restrict__ argb,
                        float* __restrict__ WcatT, float* __restrict__ biasv){
    int k = blockIdx.x;            // 0..255
    int n = threadIdx.x;           // 0..127
    if (n >= NCP) return;          // guard: block 128 wide, row 112
    float v = 0.0f;
    if (n < E_)       v = evw[(size_t)n * 256 + k];
    else if (n < 70)  v = argw[(size_t)(n - 34) * 545 + k];
    else if (n < NC_) v = argw[(size_t)(n - 70) * 545 + 256 + k];
    WcatT[(size_t)k * NCP + n] = v;
    if (k == 0){
        float bv = 0.0f;
        if (n < E_) bv = evb[n];
        else if (n < 70) bv = argb[n - 34];
        biasv[n] = bv;
    }
}

// ---- G1: XW[d][m][n] = emb[ids[m]][:] . w_ih_d[n][:] + b_ih[n] + b_hh[n] ----
// Round-12: BM=16 (was 8). gemm1 is L2-BW-bound on WT re-streams (614KB/block
// for 8 rows = 629MB total); doubling rows/block halves WT traffic. pk_fma
// (f2 ext-vector) halves FMA issue. Per-(row,col) k-chains unchanged =>
// bit-exact vs prior rounds.
__launch_bounds__(256)
__global__ void k_gemm1(const int* __restrict__ ids, const float* __restrict__ emb,
                        const float* __restrict__ WT,
                        const float* __restrict__ bihf, const float* __restrict__ bhhf,
                        const float* __restrict__ bihb, const float* __restrict__ bhhb,
                        float* __restrict__ XW){
    __shared__ __align__(16) float xs[DP_][BM_];   // [k][r], 19.5 KB
    __shared__ int ids_s[BM_];
    int d  = blockIdx.y;
    int m0 = blockIdx.x * BM_;
    int tid = threadIdx.x;         // 0..255
    if (tid < BM_) ids_s[tid] = ids[m0 + tid];
    __syncthreads();
    for (int idx = tid; idx < BM_ * DP_; idx += 256){
        int k = idx >> 4, r = idx & (BM_ - 1);
        xs[k][r] = (k < D_) ? emb[(size_t)ids_s[r] * D_ + k] : 0.0f;
    }
    __syncthreads();
    int n0 = tid, n1 = tid + 256;
    const float* w0 = WT + (size_t)d * DP_ * G_ + n0;
    const float* w1 = WT + (size_t)d * DP_ * G_ + n1;
    const float4* xs4 = (const float4*)xs;
    f2 acc0[8] = {}, acc1[8] = {};
    #pragma unroll 2
    for (int k = 0; k < D_; k++){
        float wv0 = w0[(size_t)k * G_];
        float wv1 = w1[(size_t)k * G_];
        f2 wb0 = {wv0, wv0}, wb1 = {wv1, wv1};
        #pragma unroll
        for (int rq = 0; rq < 4; rq++){
            float4 x = xs4[k * 4 + rq];
            f2 xlo = {x.x, x.y}, xhi = {x.z, x.w};
            acc0[2*rq]   = __builtin_elementwise_fma(wb0, xlo, acc0[2*rq]);
            acc0[2*rq+1] = __builtin_elementwise_fma(wb0, xhi, acc0[2*rq+1]);
            acc1[2*rq]   = __builtin_elementwise_fma(wb1, xlo, acc1[2*rq]);
            acc1[2*rq+1] = __builtin_elementwise_fma(wb1, xhi, acc1[2*rq+1]);
        }
    }
    float bias0 = d ? (bihb[n0] + bhhb[n0]) : (bihf[n0] + bhhf[n0]);
    float bias1 = d ? (bihb[n1] + bhhb[n1]) : (bihf[n1] + bhhf[n1]);
    #pragma unroll
    for (int r = 0; r < BM_; r++){
        float v0 = (r & 1) ? acc0[r >> 1].y : acc0[r >> 1].x;
        float v1 = (r & 1) ? acc1[r >> 1].y : acc1[r >> 1].x;
        XW[((size_t)d * M_ + m0 + r) * G_ + n0] = v0 + bias0;
        XW[((size_t)d * M_ + m0 + r) * G_ + n1] = v1 + bias1;
    }
}

// ---- K3: LSTM recurrence. 64 blocks = (dir,b); 512 threads = one z-row each.
// Round-12: revert to the round-7 structure (best measured: 124us — 2-barrier
// zbuf, wave-uniform gate mapping, phase B on threads 0..127) and halve the
// dominant VALU stream with v_pk_fma_f32: the 128-FMA dot becomes 64 packed
// f2 FMAs. Chains (z0,z1),(z2,z3) are the two lanes of two packed
// accumulators; final (z0+z1)+(z2+z3) preserved => bit-identical numerics.
// Keeps R5's ping-pong xw chunk prefetch (hides HBM latency under 8 steps).
#define PF(XR, CHI)                                                             \
{                                                                               \
    if ((CHI) < NCHK){                                                          \
        _Pragma("unroll")                                                       \
        for (int j = 0; j < LCH; j++){                                          \
            int s_ = (CHI) * LCH + j;                                           \
            int t_ = d ? (L_ - 1 - s_) : s_;                                    \
            XR[j] = xwn[(size_t)t_ * G_];                                       \
        }                                                                       \
    }                                                                           \
}

#define STEP8(XR, CHI)                                                          \
{                                                                               \
    _Pragma("unroll")                                                           \
    for (int j = 0; j < LCH; j++){                                              \
        int s_ = (CHI) * LCH + j;                                               \
        f2 a01 = {0.f, 0.f}, a23 = {0.f, 0.f};                                  \
        const float4* hc = (const float4*)hbuf;                                 \
        _Pragma("unroll")                                                       \
        for (int q = 0; q < 32; q++){                                           \
            float4 hv = hc[q];                                                  \
            f2 h01 = {hv.x, hv.y}, h23 = {hv.z, hv.w};                          \
            a01 = __builtin_elementwise_fma(wp[2*q],   h01, a01);               \
            a23 = __builtin_elementwise_fma(wp[2*q+1], h23, a23);               \
        }                                                                       \
        float z = XR[j] + ((a01.x + a01.y) + (a23.x + a23.y));                  \
        float v = gate_g ? tanhf(z) : sigf(z);                                  \
        zbuf[n] = v;                                                            \
        __syncthreads();                                                        \
        if (n < H_){                                                            \
            float F = zbuf[H_ + n], G = zbuf[2*H_ + n], O = zbuf[3*H_ + n];     \
            c = F * c + v * G;                                                  \
            float h = O * tanhf(c);                                             \
            hbuf[n] = h;                                                        \
            hist[(size_t)(s_) * H_ + n] = h;                                    \
        }                                                                       \
        __syncthreads();                                                        \
    }                                                                           \
}

__launch_bounds__(512, 2)
__global__ void k_lstm(const float* __restrict__ XW, const float* __restrict__ whhf,
                       const float* __restrict__ whhb, float* __restrict__ Hid){
    __shared__ __align__(16) float hbuf[H_];
    __shared__ float zbuf[G_];
    __shared__ __align__(16) float hist[L_ * H_];   // 64 KB full h history
    int bid = blockIdx.x;
    int d = bid >> 5, b = bid & 31;
    int n = threadIdx.x;           // 0..511, z-row
    bool gate_g = ((n >> 7) == 2); // rows 256..383 = g gate (tanh); wave-uniform
    const float* whh = d ? whhb : whhf;
    const f2* wr2 = (const f2*)(whh + (size_t)n * H_);
    f2 wp[64];
    #pragma unroll
    for (int q = 0; q < 64; q++) wp[q] = wr2[q];
    float c = 0.0f;
    if (n < H_) hbuf[n] = 0.0f;
    __syncthreads();
    const float* xwn = XW + ((size_t)d * M_ + (size_t)b * L_) * G_ + n;
    float xA[LCH], xB[LCH];
    PF(xA, 0)
    #pragma unroll 1
    for (int cp = 0; cp < NCHK / 2; cp++){
        PF(xB, 2 * cp + 1)
        STEP8(xA, 2 * cp)
        PF(xA, 2 * cp + 2)
        STEP8(xB, 2 * cp + 1)
    }
    // bulk flush: 128 steps x 128 h = 4096 float4, 8 per thread
    const float4* hist4 = (const float4*)hist;
    #pragma unroll
    for (int q = 0; q < 8; q++){
        int idx = n + q * 512;
        int sl = idx >> 5, n4 = idx & 31;
        int t_ = d ? (L_ - 1 - sl) : sl;
        *(float4*)(Hid + ((size_t)b * L_ + t_) * 256 + d * H_ + n4 * 4) =
            hist4[(size_t)sl * 32 + n4];
    }
}

// ---- K4: heads. One block per m. cols: 0..33 ev, 34..69 base, 70..105 t2. ----
__launch_bounds__(128)
__global__ void k_heads2(const float* __restrict__ Hid, const float* __restrict__ WcatT,
                         const float* __restrict__ biasv,
                         float* __restrict__ out0, float* __restrict__ Base,
                         float* __restrict__ T2, int* __restrict__ Evcol){
    __shared__ float hs[256];
    __shared__ float evl[E_];
    int m = blockIdx.x;
    int tid = threadIdx.x;         // 0..127
    hs[tid]       = Hid[(size_t)m * 256 + tid];
    hs[tid + 128] = Hid[(size_t)m * 256 + 128 + tid];
    __syncthreads();
    float acc = 0.0f;
    if (tid < NC_){
        const float* wc = WcatT + tid;
        for (int k = 0; k < 256; k++) acc += hs[k] * wc[(size_t)k * NCP];
        acc += biasv[tid];
    }
    if (tid < E_){
        out0[(size_t)m * E_ + tid] = acc;   // fp32 output
        evl[tid] = acc;
    } else if (tid < 70){
        Base[(size_t)m * A_ + (tid - 34)] = acc;
    } else if (tid < NC_){
        T2[(size_t)m * A_ + (tid - 70)] = acc;
    }
    __syncthreads();
    if (tid == 0){                 // first-max argmax over E=34
        float best = evl[0]; int bi = 0;
        for (int e = 1; e < E_; e++){
            float v = evl[e];
            if (v > best){ best = v; bi = e; }
        }
        Evcol[m] = bi - 1;         // -1 => ev_pred==0 (no g update)
    }
}

// ---- K5a: serial state propagation only. Snapshots (bg, mask) every CH_ steps.
// No argout stores here — that's phase 2's job.
__launch_bounds__(128)
__global__ void k_scan1(const float* __restrict__ Base, const float* __restrict__ T2,
                        const int* __restrict__ Evcol, const float* __restrict__ argw,
                        float* __restrict__ Snap, uint64_t* __restrict__ MaskSnap){
    __shared__ float t2s[L_ * A_];
    __shared__ float wgs[33 * A_];
    __shared__ int   evc[L_];
    int b = blockIdx.x;
    int l = threadIdx.x;             // 0..127
    for (int idx = l; idx < L_ * A_; idx += 128)
        t2s[idx] = T2[(size_t)b * L_ * A_ + idx];
    for (int idx = l; idx < 33 * A_; idx += 128){
        int c = idx / A_, a = idx % A_;
        wgs[idx] = argw[(size_t)a * 545 + 512 + c];
    }
    evc[l] = Evcol[b * L_ + l];
    __syncthreads();
    float bg[A_];
    {
        const float* bp = Base + ((size_t)b * L_ + l) * A_;
        #pragma unroll
        for (int a = 0; a < A_; a++) bg[a] = bp[a];
    }
    uint64_t mask = 0;
    #pragma unroll 1
    for (int i = 0; i < L_; i++){
        if ((i & (CH_ - 1)) == 0){
            int ch = i >> 3;
            float* sp = Snap + (((size_t)b * NCH + ch) * L_ + l) * A_;
            #pragma unroll
            for (int a = 0; a < A_; a++) sp[a] = bg[a];
            MaskSnap[((size_t)b * NCH + ch) * L_ + l] = mask;
        }
        const float* tr = t2s + i * A_;
        float lg0 = bg[0] + tr[0];
        float m1  = bg[1] + tr[1];
        #pragma unroll
        for (int a = 2; a < A_; a++) m1 = fmaxf(m1, bg[a] + tr[a]);
        bool apos = m1 > lg0;
        int cc = evc[i];
        if (cc >= 0 && apos && !((mask >> cc) & 1ull)){
            mask |= 1ull << cc;
            const float* wc = wgs + cc * A_;
            #pragma unroll
            for (int a = 0; a < A_; a++) bg[a] += wc[a];
        }
    }
}

// ---- K5b: parallel replay of CH_-step chunks from snapshots; does all stores.
// Bit-exact same ops as k_scan1 => identical decisions, exact state continuity.
__launch_bounds__(128)
__global__ void k_scan2(const float* __restrict__ T2, const int* __restrict__ Evcol,
                        const float* __restrict__ argw,
                        const float* __restrict__ Snap, const uint64_t* __restrict__ MaskSnap,
                        float* __restrict__ argout){
    __shared__ float t2s[CH_ * A_];
    __shared__ float wgs[33 * A_];
    __shared__ int   evc[CH_];
    int ch = blockIdx.x;             // 0..15
    int b  = blockIdx.y;             // 0..31
    int l  = threadIdx.x;            // 0..127
    int i0 = ch * CH_;
    for (int idx = l; idx < CH_ * A_; idx += 128)
        t2s[idx] = T2[((size_t)b * L_ + i0) * A_ + idx];
    for (int idx = l; idx < 33 * A_; idx += 128){
        int c = idx / A_, a = idx % A_;
        wgs[idx] = argw[(size_t)a * 545 + 512 + c];
    }
    if (l < CH_) evc[l] = Evcol[b * L_ + i0 + l];
    __syncthreads();
    float bg[A_];
    {
        const float* sp = Snap + (((size_t)b * NCH + ch) * L_ + l) * A_;
        #pragma unroll
        for (int a = 0; a < A_; a++) bg[a] = sp[a];
    }
    uint64_t mask = MaskSnap[((size_t)b * NCH + ch) * L_ + l];
    #pragma unroll 1
    for (int s = 0; s < CH_; s++){
        int i = i0 + s;
        const float* tr = t2s + s * A_;
        float lg[A_];
        #pragma unroll
        for (int a = 0; a < A_; a++) lg[a] = bg[a] + tr[a];
        float m1 = lg[1];
        #pragma unroll
        for (int a = 2; a < A_; a++) m1 = fmaxf(m1, lg[a]);
        bool apos = m1 > lg[0];
        float* op = argout + (((size_t)b * L_ + i) * L_ + l) * A_;
        #pragma unroll
        for (int q = 0; q < 9; q++){
            float4 v; v.x = lg[4*q]; v.y = lg[4*q+1]; v.z = lg[4*q+2]; v.w = lg[4*q+3];
            *(float4*)(op + 4 * q) = v;
        }
        int cc = evc[s];
        if (cc >= 0 && apos && !((mask >> cc) & 1ull)){
            mask |= 1ull << cc;
            const float* wc = wgs + cc * A_;
            #pragma unroll
            for (int a = 0; a < A_; a++) bg[a] += wc[a];
        }
    }
}

extern "C" void kernel_launch(void* const* d_in, const int* in_sizes, int n_in,
                              void* d_out, int out_size, void* d_ws, size_t ws_size,
                              hipStream_t stream){
    const int*   ids  = (const int*)  d_in[0];
    const float* emb  = (const float*)d_in[1];
    const float* wihf = (const float*)d_in[2];
    const float* whhf = (const float*)d_in[3];
    const float* bihf = (const float*)d_in[4];
    const float* bhhf = (const float*)d_in[5];
    const float* wihb = (const float*)d_in[6];
    const float* whhb = (const float*)d_in[7];
    const float* bihb = (const float*)d_in[8];
    const float* bhhb = (const float*)d_in[9];
    const float* evw  = (const float*)d_in[10];
    const float* evb  = (const float*)d_in[11];
    const float* argw = (const float*)d_in[12];
    const float* argb = (const float*)d_in[13];

    float* out0   = (float*)d_out;                 // [B,L,E] fp32
    float* argout = out0 + (size_t)M_ * E_;        // [B,L,L,A] fp32

    char* w = (char*)d_ws;                          // ~23.5 MB total
    float* WT    = (float*)w; w += (size_t)2 * DP_ * G_ * 4;   // 1.24 MB
    float* XW    = (float*)w; w += (size_t)2 * M_ * G_ * 4;    // 16.78 MB
    float* Hid   = (float*)w; w += (size_t)M_ * 256 * 4;       // 4.19 MB
    float* WcatT = (float*)w; w += (size_t)256 * NCP * 4;
    float* biasv = (float*)w; w += (size_t)NCP * 4;
    float* Base  = (float*)w; w += (size_t)M_ * A_ * 4;
    float* T2    = (float*)w; w += (size_t)M_ * A_ * 4;
    int*   Evcol = (int*)w;   w += (size_t)M_ * 4;

    // Scan snapshots alias the XW region (dead after k_lstm):
    // Snap 9.44 MB + MaskSnap 0.5 MB < 16.78 MB.
    float*    Snap     = XW;
    uint64_t* MaskSnap = (uint64_t*)(XW + (size_t)B_ * NCH * L_ * A_);

    k_prep1<<<dim3(DP_, 2), 512, 0, stream>>>(wihf, wihb, WT);
    k_prep2<<<256, 128, 0, stream>>>(evw, evb, argw, argb, WcatT, biasv);
    k_gemm1<<<dim3(M_ / BM_, 2), 256, 0, stream>>>(ids, emb, WT, bihf, bhhf, bihb, bhhb, XW);
    k_lstm<<<64, 512, 0, stream>>>(XW, whhf, whhb, Hid);
    k_heads2<<<M_, 128, 0, stream>>>(Hid, WcatT, biasv, out0, Base, T2, Evcol);
    k_scan1<<<B_, 128, 0, stream>>>(Base, T2, Evcol, argw, Snap, MaskSnap);
    k_scan2<<<dim3(NCH, B_), 128, 0, stream>>>(T2, Evcol, argw, Snap, MaskSnap, argout);
}

// Round 7
// 378.641 us; speedup vs baseline: 1.2206x; 1.0267x over previous
//
#include <hip/hip_runtime.h>
#include <hip/hip_bf16.h>
#include <stdint.h>

#define B_  32
#define L_  128
#define D_  300
#define DP_ 304
#define H_  128
#define G_  512
#define E_  34
#define A_  36
#define M_  4096   // B*L
#define NC_ 106    // 34 ev + 36 base + 36 t2
#define NCP 112    // padded col count
#define CH_ 8      // scan chunk length
#define NCH 16     // chunks per sequence
#define LCH 8      // lstm xw prefetch chunk length
#define NCHK (L_ / LCH)
#define BM_ 16     // gemm1 rows per block

typedef float f2 __attribute__((ext_vector_type(2)));

__device__ __forceinline__ float sigf(float x){ return 1.0f / (1.0f + expf(-x)); }

// LDS-only barrier: waits DS ops but leaves global (vmcnt) loads IN FLIGHT
// across the barrier — __syncthreads() would drain vmcnt(0), stalling each
// chunk's xw prefetch ~400-900cyc at the first barrier after issue.
// "memory" clobber orders all memory ops both ways; sched_barrier pins.
__device__ __forceinline__ void bar_lds(){
    asm volatile("s_waitcnt lgkmcnt(0)" ::: "memory");
    __builtin_amdgcn_s_barrier();
    __builtin_amdgcn_sched_barrier(0);
}

// ---- P1: transpose W_ih into WT[d][k][n] (k-major, zero-padded k<304) ----
__global__ void k_prep1(const float* __restrict__ wihf, const float* __restrict__ wihb,
                        float* __restrict__ WT){
    int k = blockIdx.x;            // 0..303
    int d = blockIdx.y;            // 0..1
    int n = threadIdx.x;           // 0..511
    const float* w = d ? wihb : wihf;
    WT[((size_t)d * DP_ + k) * G_ + n] = (k < D_) ? w[(size_t)n * D_ + k] : 0.0f;
}

// ---- P2: pack head weights WcatT[k][n] (256 x NCP) + bias vector ----
__global__ void k_prep2(const float* __restrict__ evw, const float* __restrict__ evb,
                        const float* __restrict__ argw, const float* __restrict__ argb,
                        float* __restrict__ WcatT, float* __restrict__ biasv){
    int k = blockIdx.x;            // 0..255
    int n = threadIdx.x;           // 0..127
    if (n >= NCP) return;          // guard: block 128 wide, row 112
    float v = 0.0f;
    if (n < E_)       v = evw[(size_t)n * 256 + k];
    else if (n < 70)  v = argw[(size_t)(n - 34) * 545 + k];
    else if (n < NC_) v = argw[(size_t)(n - 70) * 545 + 256 + k];
    WcatT[(size_t)k * NCP + n] = v;
    if (k == 0){
        float bv = 0.0f;
        if (n < E_) bv = evb[n];
        else if (n < 70) bv = argb[n - 34];
        biasv[n] = bv;
    }
}

// ---- G1: XW[d][m][n] = emb[ids[m]][:] . w_ih_d[n][:] + b_ih[n] + b_hh[n] ----
// BM=16 + pk_fma (kept from round-12; per-(row,col) k-chains bit-exact).
__launch_bounds__(256)
__global__ void k_gemm1(const int* __restrict__ ids, const float* __restrict__ emb,
                        const float* __restrict__ WT,
                        const float* __restrict__ bihf, const float* __restrict__ bhhf,
                        const float* __restrict__ bihb, const float* __restrict__ bhhb,
                        float* __restrict__ XW){
    __shared__ __align__(16) float xs[DP_][BM_];   // [k][r], 19.5 KB
    __shared__ int ids_s[BM_];
    int d  = blockIdx.y;
    int m0 = blockIdx.x * BM_;
    int tid = threadIdx.x;         // 0..255
    if (tid < BM_) ids_s[tid] = ids[m0 + tid];
    __syncthreads();
    for (int idx = tid; idx < BM_ * DP_; idx += 256){
        int k = idx >> 4, r = idx & (BM_ - 1);
        xs[k][r] = (k < D_) ? emb[(size_t)ids_s[r] * D_ + k] : 0.0f;
    }
    __syncthreads();
    int n0 = tid, n1 = tid + 256;
    const float* w0 = WT + (size_t)d * DP_ * G_ + n0;
    const float* w1 = WT + (size_t)d * DP_ * G_ + n1;
    const float4* xs4 = (const float4*)xs;
    f2 acc0[8] = {}, acc1[8] = {};
    #pragma unroll 2
    for (int k = 0; k < D_; k++){
        float wv0 = w0[(size_t)k * G_];
        float wv1 = w1[(size_t)k * G_];
        f2 wb0 = {wv0, wv0}, wb1 = {wv1, wv1};
        #pragma unroll
        for (int rq = 0; rq < 4; rq++){
            float4 x = xs4[k * 4 + rq];
            f2 xlo = {x.x, x.y}, xhi = {x.z, x.w};
            acc0[2*rq]   = __builtin_elementwise_fma(wb0, xlo, acc0[2*rq]);
            acc0[2*rq+1] = __builtin_elementwise_fma(wb0, xhi, acc0[2*rq+1]);
            acc1[2*rq]   = __builtin_elementwise_fma(wb1, xlo, acc1[2*rq]);
            acc1[2*rq+1] = __builtin_elementwise_fma(wb1, xhi, acc1[2*rq+1]);
        }
    }
    float bias0 = d ? (bihb[n0] + bhhb[n0]) : (bihf[n0] + bhhf[n0]);
    float bias1 = d ? (bihb[n1] + bhhb[n1]) : (bihf[n1] + bhhf[n1]);
    #pragma unroll
    for (int r = 0; r < BM_; r++){
        float v0 = (r & 1) ? acc0[r >> 1].y : acc0[r >> 1].x;
        float v1 = (r & 1) ? acc1[r >> 1].y : acc1[r >> 1].x;
        XW[((size_t)d * M_ + m0 + r) * G_ + n0] = v0 + bias0;
        XW[((size_t)d * M_ + m0 + r) * G_ + n1] = v1 + bias1;
    }
}

// ---- K3: LSTM recurrence. 64 blocks = (dir,b); 512 threads = one z-row each.
// Round-13: round-12 structure + bar_lds() instead of __syncthreads() inside
// the step loop, so the xw chunk prefetch stays in flight across barriers
// (vmcnt waited only at actual xr use). Numerics bit-identical.
#define PF(XR, CHI)                                                             \
{                                                                               \
    if ((CHI) < NCHK){                                                          \
        _Pragma("unroll")                                                       \
        for (int j = 0; j < LCH; j++){                                          \
            int s_ = (CHI) * LCH + j;                                           \
            int t_ = d ? (L_ - 1 - s_) : s_;                                    \
            XR[j] = xwn[(size_t)t_ * G_];                                       \
        }                                                                       \
    }                                                                           \
}

#define STEP8(XR, CHI)                                                          \
{                                                                               \
    _Pragma("unroll")                                                           \
    for (int j = 0; j < LCH; j++){                                              \
        int s_ = (CHI) * LCH + j;                                               \
        f2 a01 = {0.f, 0.f}, a23 = {0.f, 0.f};                                  \
        const float4* hc = (const float4*)hbuf;                                 \
        _Pragma("unroll")                                                       \
        for (int q = 0; q < 32; q++){                                           \
            float4 hv = hc[q];                                                  \
            f2 h01 = {hv.x, hv.y}, h23 = {hv.z, hv.w};                          \
            a01 = __builtin_elementwise_fma(wp[2*q],   h01, a01);               \
            a23 = __builtin_elementwise_fma(wp[2*q+1], h23, a23);               \
        }                                                                       \
        float z = XR[j] + ((a01.x + a01.y) + (a23.x + a23.y));                  \
        float v = gate_g ? tanhf(z) : sigf(z);                                  \
        zbuf[n] = v;                                                            \
        bar_lds();                                                              \
        if (n < H_){                                                            \
            float F = zbuf[H_ + n], G = zbuf[2*H_ + n], O = zbuf[3*H_ + n];     \
            c = F * c + v * G;                                                  \
            float h = O * tanhf(c);                                             \
            hbuf[n] = h;                                                        \
            hist[(size_t)(s_) * H_ + n] = h;                                    \
        }                                                                       \
        bar_lds();                                                              \
    }                                                                           \
}

__launch_bounds__(512, 2)
__global__ void k_lstm(const float* __restrict__ XW, const float* __restrict__ whhf,
                       const float* __restrict__ whhb, float* __restrict__ Hid){
    __shared__ __align__(16) float hbuf[H_];
    __shared__ float zbuf[G_];
    __shared__ __align__(16) float hist[L_ * H_];   // 64 KB full h history
    int bid = blockIdx.x;
    int d = bid >> 5, b = bid & 31;
    int n = threadIdx.x;           // 0..511, z-row
    bool gate_g = ((n >> 7) == 2); // rows 256..383 = g gate (tanh); wave-uniform
    const float* whh = d ? whhb : whhf;
    const f2* wr2 = (const f2*)(whh + (size_t)n * H_);
    f2 wp[64];
    #pragma unroll
    for (int q = 0; q < 64; q++) wp[q] = wr2[q];
    float c = 0.0f;
    if (n < H_) hbuf[n] = 0.0f;
    __syncthreads();
    const float* xwn = XW + ((size_t)d * M_ + (size_t)b * L_) * G_ + n;
    float xA[LCH], xB[LCH];
    PF(xA, 0)
    #pragma unroll 1
    for (int cp = 0; cp < NCHK / 2; cp++){
        PF(xB, 2 * cp + 1)
        STEP8(xA, 2 * cp)
        PF(xA, 2 * cp + 2)
        STEP8(xB, 2 * cp + 1)
    }
    // bulk flush: 128 steps x 128 h = 4096 float4, 8 per thread
    const float4* hist4 = (const float4*)hist;
    #pragma unroll
    for (int q = 0; q < 8; q++){
        int idx = n + q * 512;
        int sl = idx >> 5, n4 = idx & 31;
        int t_ = d ? (L_ - 1 - sl) : sl;
        *(float4*)(Hid + ((size_t)b * L_ + t_) * 256 + d * H_ + n4 * 4) =
            hist4[(size_t)sl * 32 + n4];
    }
}

// ---- K4: heads. One block per m. cols: 0..33 ev, 34..69 base, 70..105 t2. ----
__launch_bounds__(128)
__global__ void k_heads2(const float* __restrict__ Hid, const float* __restrict__ WcatT,
                         const float* __restrict__ biasv,
                         float* __restrict__ out0, float* __restrict__ Base,
                         float* __restrict__ T2, int* __restrict__ Evcol){
    __shared__ float hs[256];
    __shared__ float evl[E_];
    int m = blockIdx.x;
    int tid = threadIdx.x;         // 0..127
    hs[tid]       = Hid[(size_t)m * 256 + tid];
    hs[tid + 128] = Hid[(size_t)m * 256 + 128 + tid];
    __syncthreads();
    float acc = 0.0f;
    if (tid < NC_){
        const float* wc = WcatT + tid;
        for (int k = 0; k < 256; k++) acc += hs[k] * wc[(size_t)k * NCP];
        acc += biasv[tid];
    }
    if (tid < E_){
        out0[(size_t)m * E_ + tid] = acc;   // fp32 output
        evl[tid] = acc;
    } else if (tid < 70){
        Base[(size_t)m * A_ + (tid - 34)] = acc;
    } else if (tid < NC_){
        T2[(size_t)m * A_ + (tid - 70)] = acc;
    }
    __syncthreads();
    if (tid == 0){                 // first-max argmax over E=34
        float best = evl[0]; int bi = 0;
        for (int e = 1; e < E_; e++){
            float v = evl[e];
            if (v > best){ best = v; bi = e; }
        }
        Evcol[m] = bi - 1;         // -1 => ev_pred==0 (no g update)
    }
}

// ---- K5a: serial state propagation only. Snapshots (bg, mask) every CH_ steps.
__launch_bounds__(128)
__global__ void k_scan1(const float* __restrict__ Base, const float* __restrict__ T2,
                        const int* __restrict__ Evcol, const float* __restrict__ argw,
                        float* __restrict__ Snap, uint64_t* __restrict__ MaskSnap){
    __shared__ float t2s[L_ * A_];
    __shared__ float wgs[33 * A_];
    __shared__ int   evc[L_];
    int b = blockIdx.x;
    int l = threadIdx.x;             // 0..127
    for (int idx = l; idx < L_ * A_; idx += 128)
        t2s[idx] = T2[(size_t)b * L_ * A_ + idx];
    for (int idx = l; idx < 33 * A_; idx += 128){
        int c = idx / A_, a = idx % A_;
        wgs[idx] = argw[(size_t)a * 545 + 512 + c];
    }
    evc[l] = Evcol[b * L_ + l];
    __syncthreads();
    float bg[A_];
    {
        const float* bp = Base + ((size_t)b * L_ + l) * A_;
        #pragma unroll
        for (int a = 0; a < A_; a++) bg[a] = bp[a];
    }
    uint64_t mask = 0;
    #pragma unroll 1
    for (int i = 0; i < L_; i++){
        if ((i & (CH_ - 1)) == 0){
            int ch = i >> 3;
            float* sp = Snap + (((size_t)b * NCH + ch) * L_ + l) * A_;
            #pragma unroll
            for (int a = 0; a < A_; a++) sp[a] = bg[a];
            MaskSnap[((size_t)b * NCH + ch) * L_ + l] = mask;
        }
        const float* tr = t2s + i * A_;
        float lg0 = bg[0] + tr[0];
        float m1  = bg[1] + tr[1];
        #pragma unroll
        for (int a = 2; a < A_; a++) m1 = fmaxf(m1, bg[a] + tr[a]);
        bool apos = m1 > lg0;
        int cc = evc[i];
        if (cc >= 0 && apos && !((mask >> cc) & 1ull)){
            mask |= 1ull << cc;
            const float* wc = wgs + cc * A_;
            #pragma unroll
            for (int a = 0; a < A_; a++) bg[a] += wc[a];
        }
    }
}

// ---- K5b: parallel replay of CH_-step chunks from snapshots; does all stores.
// Round-13: per-step [128][36] tile staged in LDS (row pad 37, conflict-free)
// then stored as CONSECUTIVE float4s (prev: 144B-strided float4s = ~4x L2
// write transactions on 75.5MB). Same lg values -> bit-identical output.
__launch_bounds__(128)
__global__ void k_scan2(const float* __restrict__ T2, const int* __restrict__ Evcol,
                        const float* __restrict__ argw,
                        const float* __restrict__ Snap, const uint64_t* __restrict__ MaskSnap,
                        float* __restrict__ argout){
    __shared__ float t2s[CH_ * A_];
    __shared__ float wgs[33 * A_];
    __shared__ int   evc[CH_];
    __shared__ float stg[L_ * 37];   // 18.9 KB staging tile (pad 36->37)
    int ch = blockIdx.x;             // 0..15
    int b  = blockIdx.y;             // 0..31
    int l  = threadIdx.x;            // 0..127
    int i0 = ch * CH_;
    for (int idx = l; idx < CH_ * A_; idx += 128)
        t2s[idx] = T2[((size_t)b * L_ + i0) * A_ + idx];
    for (int idx = l; idx < 33 * A_; idx += 128){
        int c = idx / A_, a = idx % A_;
        wgs[idx] = argw[(size_t)a * 545 + 512 + c];
    }
    if (l < CH_) evc[l] = Evcol[b * L_ + i0 + l];
    __syncthreads();
    float bg[A_];
    {
        const float* sp = Snap + (((size_t)b * NCH + ch) * L_ + l) * A_;
        #pragma unroll
        for (int a = 0; a < A_; a++) bg[a] = sp[a];
    }
    uint64_t mask = MaskSnap[((size_t)b * NCH + ch) * L_ + l];
    #pragma unroll 1
    for (int s = 0; s < CH_; s++){
        int i = i0 + s;
        const float* tr = t2s + s * A_;
        float lg[A_];
        #pragma unroll
        for (int a = 0; a < A_; a++) lg[a] = bg[a] + tr[a];
        float m1 = lg[1];
        #pragma unroll
        for (int a = 2; a < A_; a++) m1 = fmaxf(m1, lg[a]);
        bool apos = m1 > lg[0];
        // stage this step's row into LDS
        float* sr = stg + l * 37;
        #pragma unroll
        for (int a = 0; a < A_; a++) sr[a] = lg[a];
        // bg/mask update (register-only) before the barrier
        int cc = evc[s];
        if (cc >= 0 && apos && !((mask >> cc) & 1ull)){
            mask |= 1ull << cc;
            const float* wc = wgs + cc * A_;
            #pragma unroll
            for (int a = 0; a < A_; a++) bg[a] += wc[a];
        }
        __syncthreads();
        // cooperative coalesced store: 1152 float4 = 9 per thread, consecutive
        float* op = argout + (((size_t)b * L_ + i) * L_) * A_;
        #pragma unroll
        for (int q = 0; q < 9; q++){
            int idx = l + q * 128;       // float4 index 0..1151
            int row = idx / 9, c4 = idx % 9;
            const float* s0 = stg + row * 37 + c4 * 4;
            float4 v; v.x = s0[0]; v.y = s0[1]; v.z = s0[2]; v.w = s0[3];
            *(float4*)(op + (size_t)idx * 4) = v;
        }
        __syncthreads();
    }
}

extern "C" void kernel_launch(void* const* d_in, const int* in_sizes, int n_in,
                              void* d_out, int out_size, void* d_ws, size_t ws_size,
                              hipStream_t stream){
    const int*   ids  = (const int*)  d_in[0];
    const float* emb  = (const float*)d_in[1];
    const float* wihf = (const float*)d_in[2];
    const float* whhf = (const float*)d_in[3];
    const float* bihf = (const float*)d_in[4];
    const float* bhhf = (const float*)d_in[5];
    const float* wihb = (const float*)d_in[6];
    const float* whhb = (const float*)d_in[7];
    const float* bihb = (const float*)d_in[8];
    const float* bhhb = (const float*)d_in[9];
    const float* evw  = (const float*)d_in[10];
    const float* evb  = (const float*)d_in[11];
    const float* argw = (const float*)d_in[12];
    const float* argb = (const float*)d_in[13];

    float* out0   = (float*)d_out;                 // [B,L,E] fp32
    float* argout = out0 + (size_t)M_ * E_;        // [B,L,L,A] fp32

    char* w = (char*)d_ws;                          // ~23.5 MB total
    float* WT    = (float*)w; w += (size_t)2 * DP_ * G_ * 4;   // 1.24 MB
    float* XW    = (float*)w; w += (size_t)2 * M_ * G_ * 4;    // 16.78 MB
    float* Hid   = (float*)w; w += (size_t)M_ * 256 * 4;       // 4.19 MB
    float* WcatT = (float*)w; w += (size_t)256 * NCP * 4;
    float* biasv = (float*)w; w += (size_t)NCP * 4;
    float* Base  = (float*)w; w += (size_t)M_ * A_ * 4;
    float* T2    = (float*)w; w += (size_t)M_ * A_ * 4;
    int*   Evcol = (int*)w;   w += (size_t)M_ * 4;

    // Scan snapshots alias the XW region (dead after k_lstm):
    // Snap 9.44 MB + MaskSnap 0.5 MB < 16.78 MB.
    float*    Snap     = XW;
    uint64_t* MaskSnap = (uint64_t*)(XW + (size_t)B_ * NCH * L_ * A_);

    k_prep1<<<dim3(DP_, 2), 512, 0, stream>>>(wihf, wihb, WT);
    k_prep2<<<256, 128, 0, stream>>>(evw, evb, argw, argb, WcatT, biasv);
    k_gemm1<<<dim3(M_ / BM_, 2), 256, 0, stream>>>(ids, emb, WT, bihf, bhhf, bihb, bhhb, XW);
    k_lstm<<<64, 512, 0, stream>>>(XW, whhf, whhb, Hid);
    k_heads2<<<M_, 128, 0, stream>>>(Hid, WcatT, biasv, out0, Base, T2, Evcol);
    k_scan1<<<B_, 128, 0, stream>>>(Base, T2, Evcol, argw, Snap, MaskSnap);
    k_scan2<<<dim3(NCH, B_), 128, 0, stream>>>(T2, Evcol, argw, Snap, MaskSnap, argout);
}

// Round 8
// 367.514 us; speedup vs baseline: 1.2575x; 1.0303x over previous
//
#include <hip/hip_runtime.h>
#include <hip/hip_bf16.h>
#include <stdint.h>

#define B_  32
#define L_  128
#define D_  300
#define DP_ 304
#define H_  128
#define G_  512
#define E_  34
#define A_  36
#define M_  4096   // B*L
#define NC_ 106    // 34 ev + 36 base + 36 t2
#define NCP 112    // padded col count
#define CH_ 8      // scan chunk length
#define NCH 16     // chunks per sequence
#define LCH 8      // lstm xw prefetch chunk length
#define NCHK (L_ / LCH)
#define BH_ 4      // heads2 rows per block

typedef float f2 __attribute__((ext_vector_type(2)));

__device__ __forceinline__ float sigf(float x){ return 1.0f / (1.0f + expf(-x)); }

// LDS-only barrier (measured neutral vs __syncthreads, kept: no downside).
__device__ __forceinline__ void bar_lds(){
    asm volatile("s_waitcnt lgkmcnt(0)" ::: "memory");
    __builtin_amdgcn_s_barrier();
    __builtin_amdgcn_sched_barrier(0);
}

// ---- P1: transpose W_ih into WT[d][k][n] (k-major, zero-padded k<304) ----
__global__ void k_prep1(const float* __restrict__ wihf, const float* __restrict__ wihb,
                        float* __restrict__ WT){
    int k = blockIdx.x;            // 0..303
    int d = blockIdx.y;            // 0..1
    int n = threadIdx.x;           // 0..511
    const float* w = d ? wihb : wihf;
    WT[((size_t)d * DP_ + k) * G_ + n] = (k < D_) ? w[(size_t)n * D_ + k] : 0.0f;
}

// ---- P2: pack head weights WcatT[k][n] (256 x NCP) + bias vector ----
__global__ void k_prep2(const float* __restrict__ evw, const float* __restrict__ evb,
                        const float* __restrict__ argw, const float* __restrict__ argb,
                        float* __restrict__ WcatT, float* __restrict__ biasv){
    int k = blockIdx.x;            // 0..255
    int n = threadIdx.x;           // 0..127
    if (n >= NCP) return;          // guard: block 128 wide, row 112
    float v = 0.0f;
    if (n < E_)       v = evw[(size_t)n * 256 + k];
    else if (n < 70)  v = argw[(size_t)(n - 34) * 545 + k];
    else if (n < NC_) v = argw[(size_t)(n - 70) * 545 + 256 + k];
    WcatT[(size_t)k * NCP + n] = v;
    if (k == 0){
        float bv = 0.0f;
        if (n < E_) bv = evb[n];
        else if (n < 70) bv = argb[n - 34];
        biasv[n] = bv;
    }
}

// ---- G1: XW[d][m][n] = emb[ids[m]][:] . w_ih_d[n][:] + b_ih[n] + b_hh[n] ----
// Round-14: REVERTED verbatim to the round-2 artifact (the only gemm1 version
// associated with the measured non-lstm remainder of 200us; the BM16+pk_fma
// rewrite coincides with remainder 256-271us -> hypothesis test).
__launch_bounds__(256)
__global__ void k_gemm1(const int* __restrict__ ids, const float* __restrict__ emb,
                        const float* __restrict__ WT,
                        const float* __restrict__ bihf, const float* __restrict__ bhhf,
                        const float* __restrict__ bihb, const float* __restrict__ bhhb,
                        float* __restrict__ XW){
    __shared__ __align__(16) float xs[DP_][8];   // [k][r]
    int d  = blockIdx.y;
    int m0 = blockIdx.x * 8;
    int tid = threadIdx.x;         // 0..255
    for (int idx = tid; idx < 8 * DP_; idx += 256){
        int r = idx / DP_, k = idx % DP_;
        int id = ids[m0 + r];
        xs[k][r] = (k < D_) ? emb[(size_t)id * D_ + k] : 0.0f;
    }
    __syncthreads();
    int n0 = tid, n1 = tid + 256;
    const float* w0 = WT + (size_t)d * DP_ * G_ + n0;
    const float* w1 = WT + (size_t)d * DP_ * G_ + n1;
    const float4* xs4 = (const float4*)xs;
    float acc0[8] = {}, acc1[8] = {};
    #pragma unroll 2
    for (int k = 0; k < D_; k++){
        float wv0 = w0[(size_t)k * G_];
        float wv1 = w1[(size_t)k * G_];
        float4 xA = xs4[k * 2], xB = xs4[k * 2 + 1];
        acc0[0] += xA.x * wv0; acc0[1] += xA.y * wv0;
        acc0[2] += xA.z * wv0; acc0[3] += xA.w * wv0;
        acc0[4] += xB.x * wv0; acc0[5] += xB.y * wv0;
        acc0[6] += xB.z * wv0; acc0[7] += xB.w * wv0;
        acc1[0] += xA.x * wv1; acc1[1] += xA.y * wv1;
        acc1[2] += xA.z * wv1; acc1[3] += xA.w * wv1;
        acc1[4] += xB.x * wv1; acc1[5] += xB.y * wv1;
        acc1[6] += xB.z * wv1; acc1[7] += xB.w * wv1;
    }
    float bias0 = d ? (bihb[n0] + bhhb[n0]) : (bihf[n0] + bhhf[n0]);
    float bias1 = d ? (bihb[n1] + bhhb[n1]) : (bihf[n1] + bhhf[n1]);
    for (int r = 0; r < 8; r++){
        XW[((size_t)d * M_ + m0 + r) * G_ + n0] = acc0[r] + bias0;
        XW[((size_t)d * M_ + m0 + r) * G_ + n1] = acc1[r] + bias1;
    }
}

// ---- K3: LSTM recurrence — UNCHANGED from round-13 (117.5us, at the LDS-port
// + serial-chain structural floor for this layout; 3 structures converged).
#define PF(XR, CHI)                                                             \
{                                                                               \
    if ((CHI) < NCHK){                                                          \
        _Pragma("unroll")                                                       \
        for (int j = 0; j < LCH; j++){                                          \
            int s_ = (CHI) * LCH + j;                                           \
            int t_ = d ? (L_ - 1 - s_) : s_;                                    \
            XR[j] = xwn[(size_t)t_ * G_];                                       \
        }                                                                       \
    }                                                                           \
}

#define STEP8(XR, CHI)                                                          \
{                                                                               \
    _Pragma("unroll")                                                           \
    for (int j = 0; j < LCH; j++){                                              \
        int s_ = (CHI) * LCH + j;                                               \
        f2 a01 = {0.f, 0.f}, a23 = {0.f, 0.f};                                  \
        const float4* hc = (const float4*)hbuf;                                 \
        _Pragma("unroll")                                                       \
        for (int q = 0; q < 32; q++){                                           \
            float4 hv = hc[q];                                                  \
            f2 h01 = {hv.x, hv.y}, h23 = {hv.z, hv.w};                          \
            a01 = __builtin_elementwise_fma(wp[2*q],   h01, a01);               \
            a23 = __builtin_elementwise_fma(wp[2*q+1], h23, a23);               \
        }                                                                       \
        float z = XR[j] + ((a01.x + a01.y) + (a23.x + a23.y));                  \
        float v = gate_g ? tanhf(z) : sigf(z);                                  \
        zbuf[n] = v;                                                            \
        bar_lds();                                                              \
        if (n < H_){                                                            \
            float F = zbuf[H_ + n], G = zbuf[2*H_ + n], O = zbuf[3*H_ + n];     \
            c = F * c + v * G;                                                  \
            float h = O * tanhf(c);                                             \
            hbuf[n] = h;                                                        \
            hist[(size_t)(s_) * H_ + n] = h;                                    \
        }                                                                       \
        bar_lds();                                                              \
    }                                                                           \
}

__launch_bounds__(512, 2)
__global__ void k_lstm(const float* __restrict__ XW, const float* __restrict__ whhf,
                       const float* __restrict__ whhb, float* __restrict__ Hid){
    __shared__ __align__(16) float hbuf[H_];
    __shared__ float zbuf[G_];
    __shared__ __align__(16) float hist[L_ * H_];   // 64 KB full h history
    int bid = blockIdx.x;
    int d = bid >> 5, b = bid & 31;
    int n = threadIdx.x;           // 0..511, z-row
    bool gate_g = ((n >> 7) == 2); // rows 256..383 = g gate (tanh); wave-uniform
    const float* whh = d ? whhb : whhf;
    const f2* wr2 = (const f2*)(whh + (size_t)n * H_);
    f2 wp[64];
    #pragma unroll
    for (int q = 0; q < 64; q++) wp[q] = wr2[q];
    float c = 0.0f;
    if (n < H_) hbuf[n] = 0.0f;
    __syncthreads();
    const float* xwn = XW + ((size_t)d * M_ + (size_t)b * L_) * G_ + n;
    float xA[LCH], xB[LCH];
    PF(xA, 0)
    #pragma unroll 1
    for (int cp = 0; cp < NCHK / 2; cp++){
        PF(xB, 2 * cp + 1)
        STEP8(xA, 2 * cp)
        PF(xA, 2 * cp + 2)
        STEP8(xB, 2 * cp + 1)
    }
    // bulk flush: 128 steps x 128 h = 4096 float4, 8 per thread
    const float4* hist4 = (const float4*)hist;
    #pragma unroll
    for (int q = 0; q < 8; q++){
        int idx = n + q * 512;
        int sl = idx >> 5, n4 = idx & 31;
        int t_ = d ? (L_ - 1 - sl) : sl;
        *(float4*)(Hid + ((size_t)b * L_ + t_) * 256 + d * H_ + n4 * 4) =
            hist4[(size_t)sl * 32 + n4];
    }
}

// ---- K4: heads. Round-14: 4 rows per block. hsT[k][4] staged in LDS so each
// per-k weight load (1 coalesced scalar VMEM) feeds 4 rows via one b128
// broadcast -> 4x fewer VMEM insts and 4x less WcatT L2 traffic (537->134MB).
// Per-(m,col) fma chain stays k-ascending => bit-identical outputs.
__launch_bounds__(128)
__global__ void k_heads2(const float* __restrict__ Hid, const float* __restrict__ WcatT,
                         const float* __restrict__ biasv,
                         float* __restrict__ out0, float* __restrict__ Base,
                         float* __restrict__ T2, int* __restrict__ Evcol){
    __shared__ __align__(16) float hsT[256][BH_];   // [k][r], 4 KB
    __shared__ float outs[BH_][NCP];                // staged results, 1.8 KB
    int m0 = blockIdx.x * BH_;
    int tid = threadIdx.x;         // 0..127
    #pragma unroll
    for (int r = 0; r < BH_; r++){
        hsT[tid][r]       = Hid[(size_t)(m0 + r) * 256 + tid];
        hsT[tid + 128][r] = Hid[(size_t)(m0 + r) * 256 + 128 + tid];
    }
    __syncthreads();
    if (tid < NC_){
        float acc[BH_] = {};
        const float* wc = WcatT + tid;
        for (int k = 0; k < 256; k++){
            float wv = wc[(size_t)k * NCP];
            float4 h4 = *(const float4*)&hsT[k][0];
            acc[0] += h4.x * wv;
            acc[1] += h4.y * wv;
            acc[2] += h4.z * wv;
            acc[3] += h4.w * wv;
        }
        float bv = biasv[tid];
        #pragma unroll
        for (int r = 0; r < BH_; r++) outs[r][tid] = acc[r] + bv;
    }
    __syncthreads();
    for (int idx = tid; idx < BH_ * E_; idx += 128){
        int r = idx / E_, e = idx % E_;
        out0[(size_t)(m0 + r) * E_ + e] = outs[r][e];
    }
    for (int idx = tid; idx < BH_ * A_; idx += 128){
        int r = idx / A_, a = idx % A_;
        Base[(size_t)(m0 + r) * A_ + a] = outs[r][34 + a];
        T2[(size_t)(m0 + r) * A_ + a]   = outs[r][70 + a];
    }
    if (tid < BH_){                // first-max argmax over E=34, one row each
        float best = outs[tid][0]; int bi = 0;
        for (int e = 1; e < E_; e++){
            float v = outs[tid][e];
            if (v > best){ best = v; bi = e; }
        }
        Evcol[m0 + tid] = bi - 1;  // -1 => ev_pred==0 (no g update)
    }
}

// ---- K5a: serial state propagation only. Snapshots (bg, mask) every CH_ steps.
__launch_bounds__(128)
__global__ void k_scan1(const float* __restrict__ Base, const float* __restrict__ T2,
                        const int* __restrict__ Evcol, const float* __restrict__ argw,
                        float* __restrict__ Snap, uint64_t* __restrict__ MaskSnap){
    __shared__ float t2s[L_ * A_];
    __shared__ float wgs[33 * A_];
    __shared__ int   evc[L_];
    int b = blockIdx.x;
    int l = threadIdx.x;             // 0..127
    for (int idx = l; idx < L_ * A_; idx += 128)
        t2s[idx] = T2[(size_t)b * L_ * A_ + idx];
    for (int idx = l; idx < 33 * A_; idx += 128){
        int c = idx / A_, a = idx % A_;
        wgs[idx] = argw[(size_t)a * 545 + 512 + c];
    }
    evc[l] = Evcol[b * L_ + l];
    __syncthreads();
    float bg[A_];
    {
        const float* bp = Base + ((size_t)b * L_ + l) * A_;
        #pragma unroll
        for (int a = 0; a < A_; a++) bg[a] = bp[a];
    }
    uint64_t mask = 0;
    #pragma unroll 1
    for (int i = 0; i < L_; i++){
        if ((i & (CH_ - 1)) == 0){
            int ch = i >> 3;
            float* sp = Snap + (((size_t)b * NCH + ch) * L_ + l) * A_;
            #pragma unroll
            for (int a = 0; a < A_; a++) sp[a] = bg[a];
            MaskSnap[((size_t)b * NCH + ch) * L_ + l] = mask;
        }
        const float* tr = t2s + i * A_;
        float lg0 = bg[0] + tr[0];
        float m1  = bg[1] + tr[1];
        #pragma unroll
        for (int a = 2; a < A_; a++) m1 = fmaxf(m1, bg[a] + tr[a]);
        bool apos = m1 > lg0;
        int cc = evc[i];
        if (cc >= 0 && apos && !((mask >> cc) & 1ull)){
            mask |= 1ull << cc;
            const float* wc = wgs + cc * A_;
            #pragma unroll
            for (int a = 0; a < A_; a++) bg[a] += wc[a];
        }
    }
}

// ---- K5b: parallel replay of CH_-step chunks from snapshots; does all stores.
// LDS-staged coalesced stores (round-13). Bit-exact replay of k_scan1 ops.
__launch_bounds__(128)
__global__ void k_scan2(const float* __restrict__ T2, const int* __restrict__ Evcol,
                        const float* __restrict__ argw,
                        const float* __restrict__ Snap, const uint64_t* __restrict__ MaskSnap,
                        float* __restrict__ argout){
    __shared__ float t2s[CH_ * A_];
    __shared__ float wgs[33 * A_];
    __shared__ int   evc[CH_];
    __shared__ float stg[L_ * 37];   // 18.9 KB staging tile (pad 36->37)
    int ch = blockIdx.x;             // 0..15
    int b  = blockIdx.y;             // 0..31
    int l  = threadIdx.x;            // 0..127
    int i0 = ch * CH_;
    for (int idx = l; idx < CH_ * A_; idx += 128)
        t2s[idx] = T2[((size_t)b * L_ + i0) * A_ + idx];
    for (int idx = l; idx < 33 * A_; idx += 128){
        int c = idx / A_, a = idx % A_;
        wgs[idx] = argw[(size_t)a * 545 + 512 + c];
    }
    if (l < CH_) evc[l] = Evcol[b * L_ + i0 + l];
    __syncthreads();
    float bg[A_];
    {
        const float* sp = Snap + (((size_t)b * NCH + ch) * L_ + l) * A_;
        #pragma unroll
        for (int a = 0; a < A_; a++) bg[a] = sp[a];
    }
    uint64_t mask = MaskSnap[((size_t)b * NCH + ch) * L_ + l];
    #pragma unroll 1
    for (int s = 0; s < CH_; s++){
        int i = i0 + s;
        const float* tr = t2s + s * A_;
        float lg[A_];
        #pragma unroll
        for (int a = 0; a < A_; a++) lg[a] = bg[a] + tr[a];
        float m1 = lg[1];
        #pragma unroll
        for (int a = 2; a < A_; a++) m1 = fmaxf(m1, lg[a]);
        bool apos = m1 > lg[0];
        float* sr = stg + l * 37;
        #pragma unroll
        for (int a = 0; a < A_; a++) sr[a] = lg[a];
        int cc = evc[s];
        if (cc >= 0 && apos && !((mask >> cc) & 1ull)){
            mask |= 1ull << cc;
            const float* wc = wgs + cc * A_;
            #pragma unroll
            for (int a = 0; a < A_; a++) bg[a] += wc[a];
        }
        __syncthreads();
        float* op = argout + (((size_t)b * L_ + i) * L_) * A_;
        #pragma unroll
        for (int q = 0; q < 9; q++){
            int idx = l + q * 128;       // float4 index 0..1151
            int row = idx / 9, c4 = idx % 9;
            const float* s0 = stg + row * 37 + c4 * 4;
            float4 v; v.x = s0[0]; v.y = s0[1]; v.z = s0[2]; v.w = s0[3];
            *(float4*)(op + (size_t)idx * 4) = v;
        }
        __syncthreads();
    }
}

extern "C" void kernel_launch(void* const* d_in, const int* in_sizes, int n_in,
                              void* d_out, int out_size, void* d_ws, size_t ws_size,
                              hipStream_t stream){
    const int*   ids  = (const int*)  d_in[0];
    const float* emb  = (const float*)d_in[1];
    const float* wihf = (const float*)d_in[2];
    const float* whhf = (const float*)d_in[3];
    const float* bihf = (const float*)d_in[4];
    const float* bhhf = (const float*)d_in[5];
    const float* wihb = (const float*)d_in[6];
    const float* whhb = (const float*)d_in[7];
    const float* bihb = (const float*)d_in[8];
    const float* bhhb = (const float*)d_in[9];
    const float* evw  = (const float*)d_in[10];
    const float* evb  = (const float*)d_in[11];
    const float* argw = (const float*)d_in[12];
    const float* argb = (const float*)d_in[13];

    float* out0   = (float*)d_out;                 // [B,L,E] fp32
    float* argout = out0 + (size_t)M_ * E_;        // [B,L,L,A] fp32

    char* w = (char*)d_ws;                          // ~23.5 MB total
    float* WT    = (float*)w; w += (size_t)2 * DP_ * G_ * 4;   // 1.24 MB
    float* XW    = (float*)w; w += (size_t)2 * M_ * G_ * 4;    // 16.78 MB
    float* Hid   = (float*)w; w += (size_t)M_ * 256 * 4;       // 4.19 MB
    float* WcatT = (float*)w; w += (size_t)256 * NCP * 4;
    float* biasv = (float*)w; w += (size_t)NCP * 4;
    float* Base  = (float*)w; w += (size_t)M_ * A_ * 4;
    float* T2    = (float*)w; w += (size_t)M_ * A_ * 4;
    int*   Evcol = (int*)w;   w += (size_t)M_ * 4;

    // Scan snapshots alias the XW region (dead after k_lstm):
    // Snap 9.44 MB + MaskSnap 0.5 MB < 16.78 MB.
    float*    Snap     = XW;
    uint64_t* MaskSnap = (uint64_t*)(XW + (size_t)B_ * NCH * L_ * A_);

    k_prep1<<<dim3(DP_, 2), 512, 0, stream>>>(wihf, wihb, WT);
    k_prep2<<<256, 128, 0, stream>>>(evw, evb, argw, argb, WcatT, biasv);
    k_gemm1<<<dim3(M_ / 8, 2), 256, 0, stream>>>(ids, emb, WT, bihf, bhhf, bihb, bhhb, XW);
    k_lstm<<<64, 512, 0, stream>>>(XW, whhf, whhb, Hid);
    k_heads2<<<M_ / BH_, 128, 0, stream>>>(Hid, WcatT, biasv, out0, Base, T2, Evcol);
    k_scan1<<<B_, 128, 0, stream>>>(Base, T2, Evcol, argw, Snap, MaskSnap);
    k_scan2<<<dim3(NCH, B_), 128, 0, stream>>>(T2, Evcol, argw, Snap, MaskSnap, argout);
}

// Round 9
// 359.711 us; speedup vs baseline: 1.2848x; 1.0217x over previous
//
#include <hip/hip_runtime.h>
#include <hip/hip_bf16.h>
#include <stdint.h>

#define B_  32
#define L_  128
#define D_  300
#define DP_ 304
#define H_  128
#define G_  512
#define E_  34
#define A_  36
#define M_  4096   // B*L
#define NC_ 106    // 34 ev + 36 base + 36 t2
#define NCP 112    // padded col count
#define CH_ 8      // scan chunk length
#define NCH 16     // chunks per sequence
#define LCH 8      // lstm xw prefetch chunk length
#define NCHK (L_ / LCH)
#define BH_ 8      // heads2 rows per block

typedef float f2 __attribute__((ext_vector_type(2)));

__device__ __forceinline__ float sigf(float x){ return 1.0f / (1.0f + expf(-x)); }

// LDS-only barrier (measured neutral vs __syncthreads, kept: no downside).
__device__ __forceinline__ void bar_lds(){
    asm volatile("s_waitcnt lgkmcnt(0)" ::: "memory");
    __builtin_amdgcn_s_barrier();
    __builtin_amdgcn_sched_barrier(0);
}

// ---- P: fused prep (round-15: one dispatch instead of two).
// Blocks 0..607: WT transpose (d = bid/DP_, k = bid%DP_), 512 threads.
// Blocks 608..863: WcatT pack (k = bid-608), threads 0..111 active.
__global__ void k_prep(const float* __restrict__ wihf, const float* __restrict__ wihb,
                       float* __restrict__ WT,
                       const float* __restrict__ evw, const float* __restrict__ evb,
                       const float* __restrict__ argw, const float* __restrict__ argb,
                       float* __restrict__ WcatT, float* __restrict__ biasv){
    int bid = blockIdx.x;
    int tid = threadIdx.x;
    if (bid < 2 * DP_){
        int d = bid / DP_, k = bid - d * DP_;
        const float* w = d ? wihb : wihf;
        WT[((size_t)d * DP_ + k) * G_ + tid] = (k < D_) ? w[(size_t)tid * D_ + k] : 0.0f;
    } else {
        int k = bid - 2 * DP_;         // 0..255
        int n = tid;
        if (n < NCP){
            float v = 0.0f;
            if (n < E_)       v = evw[(size_t)n * 256 + k];
            else if (n < 70)  v = argw[(size_t)(n - 34) * 545 + k];
            else if (n < NC_) v = argw[(size_t)(n - 70) * 545 + 256 + k];
            WcatT[(size_t)k * NCP + n] = v;
            if (k == 0){
                float bv = 0.0f;
                if (n < E_) bv = evb[n];
                else if (n < 70) bv = argb[n - 34];
                biasv[n] = bv;
            }
        }
    }
}

// ---- G1: XW[d][m][n] = emb[ids[m]][:] . w_ih_d[n][:] + b_ih[n] + b_hh[n] ----
// R2 artifact, untouched (round-8 showed remainder deltas vs this are noise).
__launch_bounds__(256)
__global__ void k_gemm1(const int* __restrict__ ids, const float* __restrict__ emb,
                        const float* __restrict__ WT,
                        const float* __restrict__ bihf, const float* __restrict__ bhhf,
                        const float* __restrict__ bihb, const float* __restrict__ bhhb,
                        float* __restrict__ XW){
    __shared__ __align__(16) float xs[DP_][8];   // [k][r]
    int d  = blockIdx.y;
    int m0 = blockIdx.x * 8;
    int tid = threadIdx.x;         // 0..255
    for (int idx = tid; idx < 8 * DP_; idx += 256){
        int r = idx / DP_, k = idx % DP_;
        int id = ids[m0 + r];
        xs[k][r] = (k < D_) ? emb[(size_t)id * D_ + k] : 0.0f;
    }
    __syncthreads();
    int n0 = tid, n1 = tid + 256;
    const float* w0 = WT + (size_t)d * DP_ * G_ + n0;
    const float* w1 = WT + (size_t)d * DP_ * G_ + n1;
    const float4* xs4 = (const float4*)xs;
    float acc0[8] = {}, acc1[8] = {};
    #pragma unroll 2
    for (int k = 0; k < D_; k++){
        float wv0 = w0[(size_t)k * G_];
        float wv1 = w1[(size_t)k * G_];
        float4 xA = xs4[k * 2], xB = xs4[k * 2 + 1];
        acc0[0] += xA.x * wv0; acc0[1] += xA.y * wv0;
        acc0[2] += xA.z * wv0; acc0[3] += xA.w * wv0;
        acc0[4] += xB.x * wv0; acc0[5] += xB.y * wv0;
        acc0[6] += xB.z * wv0; acc0[7] += xB.w * wv0;
        acc1[0] += xA.x * wv1; acc1[1] += xA.y * wv1;
        acc1[2] += xA.z * wv1; acc1[3] += xA.w * wv1;
        acc1[4] += xB.x * wv1; acc1[5] += xB.y * wv1;
        acc1[6] += xB.z * wv1; acc1[7] += xB.w * wv1;
    }
    float bias0 = d ? (bihb[n0] + bhhb[n0]) : (bihf[n0] + bhhf[n0]);
    float bias1 = d ? (bihb[n1] + bhhb[n1]) : (bihf[n1] + bhhf[n1]);
    for (int r = 0; r < 8; r++){
        XW[((size_t)d * M_ + m0 + r) * G_ + n0] = acc0[r] + bias0;
        XW[((size_t)d * M_ + m0 + r) * G_ + n1] = acc1[r] + bias1;
    }
}

// ---- K3: LSTM recurrence — UNCHANGED (117.5us; structural floor: LDS
// broadcast port ~770cyc/step + serial gate chain; 3 structures converged).
#define PF(XR, CHI)                                                             \
{                                                                               \
    if ((CHI) < NCHK){                                                          \
        _Pragma("unroll")                                                       \
        for (int j = 0; j < LCH; j++){                                          \
            int s_ = (CHI) * LCH + j;                                           \
            int t_ = d ? (L_ - 1 - s_) : s_;                                    \
            XR[j] = xwn[(size_t)t_ * G_];                                       \
        }                                                                       \
    }                                                                           \
}

#define STEP8(XR, CHI)                                                          \
{                                                                               \
    _Pragma("unroll")                                                           \
    for (int j = 0; j < LCH; j++){                                              \
        int s_ = (CHI) * LCH + j;                                               \
        f2 a01 = {0.f, 0.f}, a23 = {0.f, 0.f};                                  \
        const float4* hc = (const float4*)hbuf;                                 \
        _Pragma("unroll")                                                       \
        for (int q = 0; q < 32; q++){                                           \
            float4 hv = hc[q];                                                  \
            f2 h01 = {hv.x, hv.y}, h23 = {hv.z, hv.w};                          \
            a01 = __builtin_elementwise_fma(wp[2*q],   h01, a01);               \
            a23 = __builtin_elementwise_fma(wp[2*q+1], h23, a23);               \
        }                                                                       \
        float z = XR[j] + ((a01.x + a01.y) + (a23.x + a23.y));                  \
        float v = gate_g ? tanhf(z) : sigf(z);                                  \
        zbuf[n] = v;                                                            \
        bar_lds();                                                              \
        if (n < H_){                                                            \
            float F = zbuf[H_ + n], G = zbuf[2*H_ + n], O = zbuf[3*H_ + n];     \
            c = F * c + v * G;                                                  \
            float h = O * tanhf(c);                                             \
            hbuf[n] = h;                                                        \
            hist[(size_t)(s_) * H_ + n] = h;                                    \
        }                                                                       \
        bar_lds();                                                              \
    }                                                                           \
}

__launch_bounds__(512, 2)
__global__ void k_lstm(const float* __restrict__ XW, const float* __restrict__ whhf,
                       const float* __restrict__ whhb, float* __restrict__ Hid){
    __shared__ __align__(16) float hbuf[H_];
    __shared__ float zbuf[G_];
    __shared__ __align__(16) float hist[L_ * H_];   // 64 KB full h history
    int bid = blockIdx.x;
    int d = bid >> 5, b = bid & 31;
    int n = threadIdx.x;           // 0..511, z-row
    bool gate_g = ((n >> 7) == 2); // rows 256..383 = g gate (tanh); wave-uniform
    const float* whh = d ? whhb : whhf;
    const f2* wr2 = (const f2*)(whh + (size_t)n * H_);
    f2 wp[64];
    #pragma unroll
    for (int q = 0; q < 64; q++) wp[q] = wr2[q];
    float c = 0.0f;
    if (n < H_) hbuf[n] = 0.0f;
    __syncthreads();
    const float* xwn = XW + ((size_t)d * M_ + (size_t)b * L_) * G_ + n;
    float xA[LCH], xB[LCH];
    PF(xA, 0)
    #pragma unroll 1
    for (int cp = 0; cp < NCHK / 2; cp++){
        PF(xB, 2 * cp + 1)
        STEP8(xA, 2 * cp)
        PF(xA, 2 * cp + 2)
        STEP8(xB, 2 * cp + 1)
    }
    // bulk flush: 128 steps x 128 h = 4096 float4, 8 per thread
    const float4* hist4 = (const float4*)hist;
    #pragma unroll
    for (int q = 0; q < 8; q++){
        int idx = n + q * 512;
        int sl = idx >> 5, n4 = idx & 31;
        int t_ = d ? (L_ - 1 - sl) : sl;
        *(float4*)(Hid + ((size_t)b * L_ + t_) * 256 + d * H_ + n4 * 4) =
            hist4[(size_t)sl * 32 + n4];
    }
}

// ---- K4: heads. Round-15: BH=8 rows per block (halves per-k VMEM wave-insts
// again: 524K->262K). hsT[k][8] broadcast b128 reads conflict-free. Per-(m,col)
// k-ascending fma chain unchanged => bit-identical.
__launch_bounds__(128)
__global__ void k_heads2(const float* __restrict__ Hid, const float* __restrict__ WcatT,
                         const float* __restrict__ biasv,
                         float* __restrict__ out0, float* __restrict__ Base,
                         float* __restrict__ T2, int* __restrict__ Evcol){
    __shared__ __align__(16) float hsT[256][BH_];   // [k][r], 8 KB
    __shared__ float outs[BH_][NCP];                // staged results, 3.6 KB
    int m0 = blockIdx.x * BH_;
    int tid = threadIdx.x;         // 0..127
    #pragma unroll
    for (int r = 0; r < BH_; r++){
        hsT[tid][r]       = Hid[(size_t)(m0 + r) * 256 + tid];
        hsT[tid + 128][r] = Hid[(size_t)(m0 + r) * 256 + 128 + tid];
    }
    __syncthreads();
    if (tid < NC_){
        float acc[BH_] = {};
        const float* wc = WcatT + tid;
        for (int k = 0; k < 256; k++){
            float wv = wc[(size_t)k * NCP];
            float4 ha = *(const float4*)&hsT[k][0];
            float4 hb = *(const float4*)&hsT[k][4];
            acc[0] += ha.x * wv; acc[1] += ha.y * wv;
            acc[2] += ha.z * wv; acc[3] += ha.w * wv;
            acc[4] += hb.x * wv; acc[5] += hb.y * wv;
            acc[6] += hb.z * wv; acc[7] += hb.w * wv;
        }
        float bv = biasv[tid];
        #pragma unroll
        for (int r = 0; r < BH_; r++) outs[r][tid] = acc[r] + bv;
    }
    __syncthreads();
    for (int idx = tid; idx < BH_ * E_; idx += 128){
        int r = idx / E_, e = idx % E_;
        out0[(size_t)(m0 + r) * E_ + e] = outs[r][e];
    }
    for (int idx = tid; idx < BH_ * A_; idx += 128){
        int r = idx / A_, a = idx % A_;
        Base[(size_t)(m0 + r) * A_ + a] = outs[r][34 + a];
        T2[(size_t)(m0 + r) * A_ + a]   = outs[r][70 + a];
    }
    if (tid < BH_){                // first-max argmax over E=34, one row each
        float best = outs[tid][0]; int bi = 0;
        for (int e = 1; e < E_; e++){
            float v = outs[tid][e];
            if (v > best){ best = v; bi = e; }
        }
        Evcol[m0 + tid] = bi - 1;  // -1 => ev_pred==0 (no g update)
    }
}

// ---- K5a: serial state propagation only. Snapshots (bg, mask) every CH_ steps.
// Round-15: float4 loads/stores everywhere (rows are 144B-aligned); broadcast
// b128 LDS reads conflict-free. Element order unchanged => bit-identical.
__launch_bounds__(128)
__global__ void k_scan1(const float* __restrict__ Base, const float* __restrict__ T2,
                        const int* __restrict__ Evcol, const float* __restrict__ argw,
                        float* __restrict__ Snap, uint64_t* __restrict__ MaskSnap){
    __shared__ __align__(16) float t2s[L_ * A_];
    __shared__ float wgs[33 * A_];
    __shared__ int   evc[L_];
    int b = blockIdx.x;
    int l = threadIdx.x;             // 0..127
    for (int idx = l; idx < L_ * A_ / 4; idx += 128)
        *(float4*)(t2s + idx * 4) = *(const float4*)(T2 + (size_t)b * L_ * A_ + idx * 4);
    for (int idx = l; idx < 33 * A_; idx += 128){
        int c = idx / A_, a = idx % A_;
        wgs[idx] = argw[(size_t)a * 545 + 512 + c];
    }
    evc[l] = Evcol[b * L_ + l];
    __syncthreads();
    float bg[A_];
    {
        const float* bp = Base + ((size_t)b * L_ + l) * A_;
        #pragma unroll
        for (int q = 0; q < 9; q++){
            float4 v = *(const float4*)(bp + 4 * q);
            bg[4*q] = v.x; bg[4*q+1] = v.y; bg[4*q+2] = v.z; bg[4*q+3] = v.w;
        }
    }
    uint64_t mask = 0;
    #pragma unroll 1
    for (int i = 0; i < L_; i++){
        if ((i & (CH_ - 1)) == 0){
            int ch = i >> 3;
            float* sp = Snap + (((size_t)b * NCH + ch) * L_ + l) * A_;
            #pragma unroll
            for (int q = 0; q < 9; q++){
                float4 v; v.x = bg[4*q]; v.y = bg[4*q+1]; v.z = bg[4*q+2]; v.w = bg[4*q+3];
                *(float4*)(sp + 4 * q) = v;
            }
            MaskSnap[((size_t)b * NCH + ch) * L_ + l] = mask;
        }
        float trv[A_];
        #pragma unroll
        for (int q = 0; q < 9; q++){
            float4 v = *(const float4*)(t2s + i * A_ + 4 * q);
            trv[4*q] = v.x; trv[4*q+1] = v.y; trv[4*q+2] = v.z; trv[4*q+3] = v.w;
        }
        float lg0 = bg[0] + trv[0];
        float m1  = bg[1] + trv[1];
        #pragma unroll
        for (int a = 2; a < A_; a++) m1 = fmaxf(m1, bg[a] + trv[a]);
        bool apos = m1 > lg0;
        int cc = evc[i];
        if (cc >= 0 && apos && !((mask >> cc) & 1ull)){
            mask |= 1ull << cc;
            const float* wc = wgs + cc * A_;
            #pragma unroll
            for (int a = 0; a < A_; a++) bg[a] += wc[a];
        }
    }
}

// ---- K5b: parallel replay of CH_-step chunks from snapshots; does all stores.
// LDS-staged coalesced stores + float4 loads. Bit-exact replay of k_scan1 ops.
__launch_bounds__(128)
__global__ void k_scan2(const float* __restrict__ T2, const int* __restrict__ Evcol,
                        const float* __restrict__ argw,
                        const float* __restrict__ Snap, const uint64_t* __restrict__ MaskSnap,
                        float* __restrict__ argout){
    __shared__ __align__(16) float t2s[CH_ * A_];
    __shared__ float wgs[33 * A_];
    __shared__ int   evc[CH_];
    __shared__ float stg[L_ * 37];   // 18.9 KB staging tile (pad 36->37)
    int ch = blockIdx.x;             // 0..15
    int b  = blockIdx.y;             // 0..31
    int l  = threadIdx.x;            // 0..127
    int i0 = ch * CH_;
    for (int idx = l; idx < CH_ * A_ / 4; idx += 128)
        *(float4*)(t2s + idx * 4) =
            *(const float4*)(T2 + ((size_t)b * L_ + i0) * A_ + idx * 4);
    for (int idx = l; idx < 33 * A_; idx += 128){
        int c = idx / A_, a = idx % A_;
        wgs[idx] = argw[(size_t)a * 545 + 512 + c];
    }
    if (l < CH_) evc[l] = Evcol[b * L_ + i0 + l];
    __syncthreads();
    float bg[A_];
    {
        const float* sp = Snap + (((size_t)b * NCH + ch) * L_ + l) * A_;
        #pragma unroll
        for (int q = 0; q < 9; q++){
            float4 v = *(const float4*)(sp + 4 * q);
            bg[4*q] = v.x; bg[4*q+1] = v.y; bg[4*q+2] = v.z; bg[4*q+3] = v.w;
        }
    }
    uint64_t mask = MaskSnap[((size_t)b * NCH + ch) * L_ + l];
    #pragma unroll 1
    for (int s = 0; s < CH_; s++){
        int i = i0 + s;
        float trv[A_];
        #pragma unroll
        for (int q = 0; q < 9; q++){
            float4 v = *(const float4*)(t2s + s * A_ + 4 * q);
            trv[4*q] = v.x; trv[4*q+1] = v.y; trv[4*q+2] = v.z; trv[4*q+3] = v.w;
        }
        float lg[A_];
        #pragma unroll
        for (int a = 0; a < A_; a++) lg[a] = bg[a] + trv[a];
        float m1 = lg[1];
        #pragma unroll
        for (int a = 2; a < A_; a++) m1 = fmaxf(m1, lg[a]);
        bool apos = m1 > lg[0];
        float* sr = stg + l * 37;
        #pragma unroll
        for (int a = 0; a < A_; a++) sr[a] = lg[a];
        int cc = evc[s];
        if (cc >= 0 && apos && !((mask >> cc) & 1ull)){
            mask |= 1ull << cc;
            const float* wc = wgs + cc * A_;
            #pragma unroll
            for (int a = 0; a < A_; a++) bg[a] += wc[a];
        }
        __syncthreads();
        float* op = argout + (((size_t)b * L_ + i) * L_) * A_;
        #pragma unroll
        for (int q = 0; q < 9; q++){
            int idx = l + q * 128;       // float4 index 0..1151
            int row = idx / 9, c4 = idx % 9;
            const float* s0 = stg + row * 37 + c4 * 4;
            float4 v; v.x = s0[0]; v.y = s0[1]; v.z = s0[2]; v.w = s0[3];
            *(float4*)(op + (size_t)idx * 4) = v;
        }
        __syncthreads();
    }
}

extern "C" void kernel_launch(void* const* d_in, const int* in_sizes, int n_in,
                              void* d_out, int out_size, void* d_ws, size_t ws_size,
                              hipStream_t stream){
    const int*   ids  = (const int*)  d_in[0];
    const float* emb  = (const float*)d_in[1];
    const float* wihf = (const float*)d_in[2];
    const float* whhf = (const float*)d_in[3];
    const float* bihf = (const float*)d_in[4];
    const float* bhhf = (const float*)d_in[5];
    const float* wihb = (const float*)d_in[6];
    const float* whhb = (const float*)d_in[7];
    const float* bihb = (const float*)d_in[8];
    const float* bhhb = (const float*)d_in[9];
    const float* evw  = (const float*)d_in[10];
    const float* evb  = (const float*)d_in[11];
    const float* argw = (const float*)d_in[12];
    const float* argb = (const float*)d_in[13];

    float* out0   = (float*)d_out;                 // [B,L,E] fp32
    float* argout = out0 + (size_t)M_ * E_;        // [B,L,L,A] fp32

    char* w = (char*)d_ws;                          // ~23.5 MB total
    float* WT    = (float*)w; w += (size_t)2 * DP_ * G_ * 4;   // 1.24 MB
    float* XW    = (float*)w; w += (size_t)2 * M_ * G_ * 4;    // 16.78 MB
    float* Hid   = (float*)w; w += (size_t)M_ * 256 * 4;       // 4.19 MB
    float* WcatT = (float*)w; w += (size_t)256 * NCP * 4;
    float* biasv = (float*)w; w += (size_t)NCP * 4;
    float* Base  = (float*)w; w += (size_t)M_ * A_ * 4;
    float* T2    = (float*)w; w += (size_t)M_ * A_ * 4;
    int*   Evcol = (int*)w;   w += (size_t)M_ * 4;

    // Scan snapshots alias the XW region (dead after k_lstm):
    // Snap 9.44 MB + MaskSnap 0.5 MB < 16.78 MB.
    float*    Snap     = XW;
    uint64_t* MaskSnap = (uint64_t*)(XW + (size_t)B_ * NCH * L_ * A_);

    k_prep<<<2 * DP_ + 256, 512, 0, stream>>>(wihf, wihb, WT, evw, evb, argw, argb,
                                              WcatT, biasv);
    k_gemm1<<<dim3(M_ / 8, 2), 256, 0, stream>>>(ids, emb, WT, bihf, bhhf, bihb, bhhb, XW);
    k_lstm<<<64, 512, 0, stream>>>(XW, whhf, whhb, Hid);
    k_heads2<<<M_ / BH_, 128, 0, stream>>>(Hid, WcatT, biasv, out0, Base, T2, Evcol);
    k_scan1<<<B_, 128, 0, stream>>>(Base, T2, Evcol, argw, Snap, MaskSnap);
    k_scan2<<<dim3(NCH, B_), 128, 0, stream>>>(T2, Evcol, argw, Snap, MaskSnap, argout);
}

// Round 10
// 357.129 us; speedup vs baseline: 1.2941x; 1.0072x over previous
//
#include <hip/hip_runtime.h>
#include <hip/hip_bf16.h>
#include <stdint.h>

#define B_  32
#define L_  128
#define D_  300
#define DP_ 304
#define H_  128
#define G_  512
#define E_  34
#define A_  36
#define M_  4096   // B*L
#define NC_ 106    // 34 ev + 36 base + 36 t2
#define NCP 112    // padded col count
#define CH_ 8      // scan chunk length
#define NCH 16     // chunks per sequence
#define LCH 8      // lstm xw prefetch chunk length
#define NCHK (L_ / LCH)
#define BH_ 8      // heads2 rows per block

typedef float f2 __attribute__((ext_vector_type(2)));

__device__ __forceinline__ float sigf(float x){ return 1.0f / (1.0f + expf(-x)); }

// LDS-only barrier (measured neutral vs __syncthreads, kept: no downside).
__device__ __forceinline__ void bar_lds(){
    asm volatile("s_waitcnt lgkmcnt(0)" ::: "memory");
    __builtin_amdgcn_s_barrier();
    __builtin_amdgcn_sched_barrier(0);
}

// ---- P: fused prep.
// Blocks 0..607: WT transpose (d = bid/DP_, k = bid%DP_), 512 threads.
// Blocks 608..863: WcatT pack (k = bid-608), threads 0..111 active.
__global__ void k_prep(const float* __restrict__ wihf, const float* __restrict__ wihb,
                       float* __restrict__ WT,
                       const float* __restrict__ evw, const float* __restrict__ evb,
                       const float* __restrict__ argw, const float* __restrict__ argb,
                       float* __restrict__ WcatT, float* __restrict__ biasv){
    int bid = blockIdx.x;
    int tid = threadIdx.x;
    if (bid < 2 * DP_){
        int d = bid / DP_, k = bid - d * DP_;
        const float* w = d ? wihb : wihf;
        WT[((size_t)d * DP_ + k) * G_ + tid] = (k < D_) ? w[(size_t)tid * D_ + k] : 0.0f;
    } else {
        int k = bid - 2 * DP_;         // 0..255
        int n = tid;
        if (n < NCP){
            float v = 0.0f;
            if (n < E_)       v = evw[(size_t)n * 256 + k];
            else if (n < 70)  v = argw[(size_t)(n - 34) * 545 + k];
            else if (n < NC_) v = argw[(size_t)(n - 70) * 545 + 256 + k];
            WcatT[(size_t)k * NCP + n] = v;
            if (k == 0){
                float bv = 0.0f;
                if (n < E_) bv = evb[n];
                else if (n < 70) bv = argb[n - 34];
                biasv[n] = bv;
            }
        }
    }
}

// ---- G1: XW[d][m][n] = emb[ids[m]][:] . w_ih_d[n][:] + b_ih[n] + b_hh[n] ----
__launch_bounds__(256)
__global__ void k_gemm1(const int* __restrict__ ids, const float* __restrict__ emb,
                        const float* __restrict__ WT,
                        const float* __restrict__ bihf, const float* __restrict__ bhhf,
                        const float* __restrict__ bihb, const float* __restrict__ bhhb,
                        float* __restrict__ XW){
    __shared__ __align__(16) float xs[DP_][8];   // [k][r]
    int d  = blockIdx.y;
    int m0 = blockIdx.x * 8;
    int tid = threadIdx.x;         // 0..255
    for (int idx = tid; idx < 8 * DP_; idx += 256){
        int r = idx / DP_, k = idx % DP_;
        int id = ids[m0 + r];
        xs[k][r] = (k < D_) ? emb[(size_t)id * D_ + k] : 0.0f;
    }
    __syncthreads();
    int n0 = tid, n1 = tid + 256;
    const float* w0 = WT + (size_t)d * DP_ * G_ + n0;
    const float* w1 = WT + (size_t)d * DP_ * G_ + n1;
    const float4* xs4 = (const float4*)xs;
    float acc0[8] = {}, acc1[8] = {};
    #pragma unroll 2
    for (int k = 0; k < D_; k++){
        float wv0 = w0[(size_t)k * G_];
        float wv1 = w1[(size_t)k * G_];
        float4 xA = xs4[k * 2], xB = xs4[k * 2 + 1];
        acc0[0] += xA.x * wv0; acc0[1] += xA.y * wv0;
        acc0[2] += xA.z * wv0; acc0[3] += xA.w * wv0;
        acc0[4] += xB.x * wv0; acc0[5] += xB.y * wv0;
        acc0[6] += xB.z * wv0; acc0[7] += xB.w * wv0;
        acc1[0] += xA.x * wv1; acc1[1] += xA.y * wv1;
        acc1[2] += xA.z * wv1; acc1[3] += xA.w * wv1;
        acc1[4] += xB.x * wv1; acc1[5] += xB.y * wv1;
        acc1[6] += xB.z * wv1; acc1[7] += xB.w * wv1;
    }
    float bias0 = d ? (bihb[n0] + bhhb[n0]) : (bihf[n0] + bhhf[n0]);
    float bias1 = d ? (bihb[n1] + bhhb[n1]) : (bihf[n1] + bhhf[n1]);
    for (int r = 0; r < 8; r++){
        XW[((size_t)d * M_ + m0 + r) * G_ + n0] = acc0[r] + bias0;
        XW[((size_t)d * M_ + m0 + r) * G_ + n1] = acc1[r] + bias1;
    }
}

// ---- K3: LSTM recurrence. Round-16: halve the LDS-broadcast inst stream.
// Diagnosis: step time ~2200cyc vs ~330cyc VALU issue -> the 256 broadcast
// ds_read_b128/CU/step (8 waves x 32) are the floor (~6-12cyc each on the
// per-CU LDS pipe). Fix: thread t owns rows (t>>1, (t>>1)+256) over K-half
// (t&1): 16 b128/thread -> 128 DS insts/CU/step, same 64 pk_fma/thread.
//  * K-halves combined by 2x __shfl_xor(.,1) (adjacent lanes).
//  * Weights = 128 VGPR/thread -> fits 256-reg cap at (512,2) (R2's AGPR
//    confound removed).
//  * even lanes read h[0..63] from copy A (banks 4q..4q+3), odd lanes read
//    h[64..127] from copy B at float 196 (banks 4q+4..4q+7) -> disjoint
//    banks (R4-proven phased-copy trick; avoids R3's 8.4M conflicts).
//  * gate pairing keeps nonlinearity wave-uniform: t<256 -> (i,g): vB=tanh;
//    t>=256 -> (f,o): vB=sig.  Phase B on even t<256 (u = t>>1).
#define PF(XR_A, XR_B, CHI)                                                     \
{                                                                               \
    if ((CHI) < NCHK){                                                          \
        _Pragma("unroll")                                                       \
        for (int j = 0; j < LCH; j++){                                          \
            int s_ = (CHI) * LCH + j;                                           \
            int t_ = d ? (L_ - 1 - s_) : s_;                                    \
            XR_A[j] = xwA[(size_t)t_ * G_];                                     \
            XR_B[j] = xwB[(size_t)t_ * G_];                                     \
        }                                                                       \
    }                                                                           \
}

#define STEP8(XR_A, XR_B, CHI)                                                  \
{                                                                               \
    _Pragma("unroll")                                                           \
    for (int j = 0; j < LCH; j++){                                              \
        int s_ = (CHI) * LCH + j;                                               \
        f2 aA0 = {0.f, 0.f}, aA1 = {0.f, 0.f};                                  \
        f2 aB0 = {0.f, 0.f}, aB1 = {0.f, 0.f};                                  \
        _Pragma("unroll")                                                       \
        for (int q = 0; q < 16; q++){                                           \
            float4 hv = hc[q];                                                  \
            f2 h01 = {hv.x, hv.y}, h23 = {hv.z, hv.w};                          \
            aA0 = __builtin_elementwise_fma(wA[2*q],   h01, aA0);               \
            aA1 = __builtin_elementwise_fma(wA[2*q+1], h23, aA1);               \
            aB0 = __builtin_elementwise_fma(wB[2*q],   h01, aB0);               \
            aB1 = __builtin_elementwise_fma(wB[2*q+1], h23, aB1);               \
        }                                                                       \
        float pA = (aA0.x + aA0.y) + (aA1.x + aA1.y);                           \
        float pB = (aB0.x + aB0.y) + (aB1.x + aB1.y);                           \
        float oA = __shfl_xor(pA, 1);                                           \
        float oB = __shfl_xor(pB, 1);                                           \
        float zA = XR_A[j] + (pA + oA);                                         \
        float zB = XR_B[j] + (pB + oB);                                         \
        float vA = sigf(zA);                                                    \
        float vB = glow ? tanhf(zB) : sigf(zB);                                 \
        if (evenHi){ zbufF[u2] = vA; zbufO[u2] = vB; }                          \
        bar_lds();                                                              \
        if (evenLo){                                                            \
            float F = zbufF[u2], O = zbufO[u2];                                 \
            c = F * c + vA * vB;                                                \
            float h = O * tanhf(c);                                             \
            hball[u2] = h; hball[132 + u2] = h;                                 \
            hist[(size_t)(s_) * H_ + u2] = h;                                   \
        }                                                                       \
        bar_lds();                                                              \
    }                                                                           \
}

__launch_bounds__(512, 2)
__global__ void k_lstm(const float* __restrict__ XW, const float* __restrict__ whhf,
                       const float* __restrict__ whhb, float* __restrict__ Hid){
    __shared__ __align__(16) float hball[260];      // h copy A @0, copy B @132
    __shared__ float zbufF[H_], zbufO[H_];
    __shared__ __align__(16) float hist[L_ * H_];   // 64 KB full h history
    int bid = blockIdx.x;
    int d = bid >> 5, b = bid & 31;
    int t = threadIdx.x;           // 0..511
    int rowA = t >> 1;             // 0..255
    int rowB = rowA + 256;
    int hf   = t & 1;              // K-half
    bool glow   = (t < 256);                 // rows (i,g): vB = tanh (wave-uniform)
    bool evenLo = (hf == 0) && (t < 256);    // phase-B owner, u = t>>1
    bool evenHi = (hf == 0) && (t >= 256);   // F,O publisher, u = (t>>1)-128
    int u2 = rowA & 127;
    const float* whh = d ? whhb : whhf;
    const f2* wrA = (const f2*)(whh + (size_t)rowA * H_ + hf * 64);
    const f2* wrB = (const f2*)(whh + (size_t)rowB * H_ + hf * 64);
    f2 wA[32], wB[32];
    #pragma unroll
    for (int q = 0; q < 32; q++){ wA[q] = wrA[q]; wB[q] = wrB[q]; }
    // even lanes (hf=0): h[0..63] from copy A @0; odd lanes: h[64..127] from
    // copy B @196 floats -> bank sets {4q..4q+3} vs {4q+4..4q+7}, disjoint.
    const float4* hc = (const float4*)(hball + (hf ? 196 : 0));
    float c = 0.0f;
    if (t < H_){ hball[t] = 0.0f; hball[132 + t] = 0.0f; }
    __syncthreads();
    const float* xwA = XW + ((size_t)d * M_ + (size_t)b * L_) * G_ + rowA;
    const float* xwB = xwA + 256;
    float xa[LCH], xb[LCH], ya[LCH], yb[LCH];
    PF(xa, xb, 0)
    #pragma unroll 1
    for (int cp = 0; cp < NCHK / 2; cp++){
        PF(ya, yb, 2 * cp + 1)
        STEP8(xa, xb, 2 * cp)
        PF(xa, xb, 2 * cp + 2)
        STEP8(ya, yb, 2 * cp + 1)
    }
    // bulk flush: 128 steps x 128 h = 4096 float4, 8 per thread
    const float4* hist4 = (const float4*)hist;
    #pragma unroll
    for (int q = 0; q < 8; q++){
        int idx = t + q * 512;
        int sl = idx >> 5, n4 = idx & 31;
        int t_ = d ? (L_ - 1 - sl) : sl;
        *(float4*)(Hid + ((size_t)b * L_ + t_) * 256 + d * H_ + n4 * 4) =
            hist4[(size_t)sl * 32 + n4];
    }
}

// ---- K4: heads. BH=8 rows per block; hsT[k][8] broadcast b128 conflict-free.
__launch_bounds__(128)
__global__ void k_heads2(const float* __restrict__ Hid, const float* __restrict__ WcatT,
                         const float* __restrict__ biasv,
                         float* __restrict__ out0, float* __restrict__ Base,
                         float* __restrict__ T2, int* __restrict__ Evcol){
    __shared__ __align__(16) float hsT[256][BH_];   // [k][r], 8 KB
    __shared__ float outs[BH_][NCP];                // staged results, 3.6 KB
    int m0 = blockIdx.x * BH_;
    int tid = threadIdx.x;         // 0..127
    #pragma unroll
    for (int r = 0; r < BH_; r++){
        hsT[tid][r]       = Hid[(size_t)(m0 + r) * 256 + tid];
        hsT[tid + 128][r] = Hid[(size_t)(m0 + r) * 256 + 128 + tid];
    }
    __syncthreads();
    if (tid < NC_){
        float acc[BH_] = {};
        const float* wc = WcatT + tid;
        for (int k = 0; k < 256; k++){
            float wv = wc[(size_t)k * NCP];
            float4 ha = *(const float4*)&hsT[k][0];
            float4 hb = *(const float4*)&hsT[k][4];
            acc[0] += ha.x * wv; acc[1] += ha.y * wv;
            acc[2] += ha.z * wv; acc[3] += ha.w * wv;
            acc[4] += hb.x * wv; acc[5] += hb.y * wv;
            acc[6] += hb.z * wv; acc[7] += hb.w * wv;
        }
        float bv = biasv[tid];
        #pragma unroll
        for (int r = 0; r < BH_; r++) outs[r][tid] = acc[r] + bv;
    }
    __syncthreads();
    for (int idx = tid; idx < BH_ * E_; idx += 128){
        int r = idx / E_, e = idx % E_;
        out0[(size_t)(m0 + r) * E_ + e] = outs[r][e];
    }
    for (int idx = tid; idx < BH_ * A_; idx += 128){
        int r = idx / A_, a = idx % A_;
        Base[(size_t)(m0 + r) * A_ + a] = outs[r][34 + a];
        T2[(size_t)(m0 + r) * A_ + a]   = outs[r][70 + a];
    }
    if (tid < BH_){                // first-max argmax over E=34, one row each
        float best = outs[tid][0]; int bi = 0;
        for (int e = 1; e < E_; e++){
            float v = outs[tid][e];
            if (v > best){ best = v; bi = e; }
        }
        Evcol[m0 + tid] = bi - 1;  // -1 => ev_pred==0 (no g update)
    }
}

// ---- K5a: serial state propagation only. Snapshots (bg, mask) every CH_ steps.
__launch_bounds__(128)
__global__ void k_scan1(const float* __restrict__ Base, const float* __restrict__ T2,
                        const int* __restrict__ Evcol, const float* __restrict__ argw,
                        float* __restrict__ Snap, uint64_t* __restrict__ MaskSnap){
    __shared__ __align__(16) float t2s[L_ * A_];
    __shared__ float wgs[33 * A_];
    __shared__ int   evc[L_];
    int b = blockIdx.x;
    int l = threadIdx.x;             // 0..127
    for (int idx = l; idx < L_ * A_ / 4; idx += 128)
        *(float4*)(t2s + idx * 4) = *(const float4*)(T2 + (size_t)b * L_ * A_ + idx * 4);
    for (int idx = l; idx < 33 * A_; idx += 128){
        int c = idx / A_, a = idx % A_;
        wgs[idx] = argw[(size_t)a * 545 + 512 + c];
    }
    evc[l] = Evcol[b * L_ + l];
    __syncthreads();
    float bg[A_];
    {
        const float* bp = Base + ((size_t)b * L_ + l) * A_;
        #pragma unroll
        for (int q = 0; q < 9; q++){
            float4 v = *(const float4*)(bp + 4 * q);
            bg[4*q] = v.x; bg[4*q+1] = v.y; bg[4*q+2] = v.z; bg[4*q+3] = v.w;
        }
    }
    uint64_t mask = 0;
    #pragma unroll 1
    for (int i = 0; i < L_; i++){
        if ((i & (CH_ - 1)) == 0){
            int ch = i >> 3;
            float* sp = Snap + (((size_t)b * NCH + ch) * L_ + l) * A_;
            #pragma unroll
            for (int q = 0; q < 9; q++){
                float4 v; v.x = bg[4*q]; v.y = bg[4*q+1]; v.z = bg[4*q+2]; v.w = bg[4*q+3];
                *(float4*)(sp + 4 * q) = v;
            }
            MaskSnap[((size_t)b * NCH + ch) * L_ + l] = mask;
        }
        float trv[A_];
        #pragma unroll
        for (int q = 0; q < 9; q++){
            float4 v = *(const float4*)(t2s + i * A_ + 4 * q);
            trv[4*q] = v.x; trv[4*q+1] = v.y; trv[4*q+2] = v.z; trv[4*q+3] = v.w;
        }
        float lg0 = bg[0] + trv[0];
        float m1  = bg[1] + trv[1];
        #pragma unroll
        for (int a = 2; a < A_; a++) m1 = fmaxf(m1, bg[a] + trv[a]);
        bool apos = m1 > lg0;
        int cc = evc[i];
        if (cc >= 0 && apos && !((mask >> cc) & 1ull)){
            mask |= 1ull << cc;
            const float* wc = wgs + cc * A_;
            #pragma unroll
            for (int a = 0; a < A_; a++) bg[a] += wc[a];
        }
    }
}

// ---- K5b: parallel replay of CH_-step chunks from snapshots; does all stores.
__launch_bounds__(128)
__global__ void k_scan2(const float* __restrict__ T2, const int* __restrict__ Evcol,
                        const float* __restrict__ argw,
                        const float* __restrict__ Snap, const uint64_t* __restrict__ MaskSnap,
                        float* __restrict__ argout){
    __shared__ __align__(16) float t2s[CH_ * A_];
    __shared__ float wgs[33 * A_];
    __shared__ int   evc[CH_];
    __shared__ float stg[L_ * 37];   // 18.9 KB staging tile (pad 36->37)
    int ch = blockIdx.x;             // 0..15
    int b  = blockIdx.y;             // 0..31
    int l  = threadIdx.x;            // 0..127
    int i0 = ch * CH_;
    for (int idx = l; idx < CH_ * A_ / 4; idx += 128)
        *(float4*)(t2s + idx * 4) =
            *(const float4*)(T2 + ((size_t)b * L_ + i0) * A_ + idx * 4);
    for (int idx = l; idx < 33 * A_; idx += 128){
        int c = idx / A_, a = idx % A_;
        wgs[idx] = argw[(size_t)a * 545 + 512 + c];
    }
    if (l < CH_) evc[l] = Evcol[b * L_ + i0 + l];
    __syncthreads();
    float bg[A_];
    {
        const float* sp = Snap + (((size_t)b * NCH + ch) * L_ + l) * A_;
        #pragma unroll
        for (int q = 0; q < 9; q++){
            float4 v = *(const float4*)(sp + 4 * q);
            bg[4*q] = v.x; bg[4*q+1] = v.y; bg[4*q+2] = v.z; bg[4*q+3] = v.w;
        }
    }
    uint64_t mask = MaskSnap[((size_t)b * NCH + ch) * L_ + l];
    #pragma unroll 1
    for (int s = 0; s < CH_; s++){
        int i = i0 + s;
        float trv[A_];
        #pragma unroll
        for (int q = 0; q < 9; q++){
            float4 v = *(const float4*)(t2s + s * A_ + 4 * q);
            trv[4*q] = v.x; trv[4*q+1] = v.y; trv[4*q+2] = v.z; trv[4*q+3] = v.w;
        }
        float lg[A_];
        #pragma unroll
        for (int a = 0; a < A_; a++) lg[a] = bg[a] + trv[a];
        float m1 = lg[1];
        #pragma unroll
        for (int a = 2; a < A_; a++) m1 = fmaxf(m1, lg[a]);
        bool apos = m1 > lg[0];
        float* sr = stg + l * 37;
        #pragma unroll
        for (int a = 0; a < A_; a++) sr[a] = lg[a];
        int cc = evc[s];
        if (cc >= 0 && apos && !((mask >> cc) & 1ull)){
            mask |= 1ull << cc;
            const float* wc = wgs + cc * A_;
            #pragma unroll
            for (int a = 0; a < A_; a++) bg[a] += wc[a];
        }
        __syncthreads();
        float* op = argout + (((size_t)b * L_ + i) * L_) * A_;
        #pragma unroll
        for (int q = 0; q < 9; q++){
            int idx = l + q * 128;       // float4 index 0..1151
            int row = idx / 9, c4 = idx % 9;
            const float* s0 = stg + row * 37 + c4 * 4;
            float4 v; v.x = s0[0]; v.y = s0[1]; v.z = s0[2]; v.w = s0[3];
            *(float4*)(op + (size_t)idx * 4) = v;
        }
        __syncthreads();
    }
}

extern "C" void kernel_launch(void* const* d_in, const int* in_sizes, int n_in,
                              void* d_out, int out_size, void* d_ws, size_t ws_size,
                              hipStream_t stream){
    const int*   ids  = (const int*)  d_in[0];
    const float* emb  = (const float*)d_in[1];
    const float* wihf = (const float*)d_in[2];
    const float* whhf = (const float*)d_in[3];
    const float* bihf = (const float*)d_in[4];
    const float* bhhf = (const float*)d_in[5];
    const float* wihb = (const float*)d_in[6];
    const float* whhb = (const float*)d_in[7];
    const float* bihb = (const float*)d_in[8];
    const float* bhhb = (const float*)d_in[9];
    const float* evw  = (const float*)d_in[10];
    const float* evb  = (const float*)d_in[11];
    const float* argw = (const float*)d_in[12];
    const float* argb = (const float*)d_in[13];

    float* out0   = (float*)d_out;                 // [B,L,E] fp32
    float* argout = out0 + (size_t)M_ * E_;        // [B,L,L,A] fp32

    char* w = (char*)d_ws;                          // ~23.5 MB total
    float* WT    = (float*)w; w += (size_t)2 * DP_ * G_ * 4;   // 1.24 MB
    float* XW    = (float*)w; w += (size_t)2 * M_ * G_ * 4;    // 16.78 MB
    float* Hid   = (float*)w; w += (size_t)M_ * 256 * 4;       // 4.19 MB
    float* WcatT = (float*)w; w += (size_t)256 * NCP * 4;
    float* biasv = (float*)w; w += (size_t)NCP * 4;
    float* Base  = (float*)w; w += (size_t)M_ * A_ * 4;
    float* T2    = (float*)w; w += (size_t)M_ * A_ * 4;
    int*   Evcol = (int*)w;   w += (size_t)M_ * 4;

    // Scan snapshots alias the XW region (dead after k_lstm):
    // Snap 9.44 MB + MaskSnap 0.5 MB < 16.78 MB.
    float*    Snap     = XW;
    uint64_t* MaskSnap = (uint64_t*)(XW + (size_t)B_ * NCH * L_ * A_);

    k_prep<<<2 * DP_ + 256, 512, 0, stream>>>(wihf, wihb, WT, evw, evb, argw, argb,
                                              WcatT, biasv);
    k_gemm1<<<dim3(M_ / 8, 2), 256, 0, stream>>>(ids, emb, WT, bihf, bhhf, bihb, bhhb, XW);
    k_lstm<<<64, 512, 0, stream>>>(XW, whhf, whhb, Hid);
    k_heads2<<<M_ / BH_, 128, 0, stream>>>(Hid, WcatT, biasv, out0, Base, T2, Evcol);
    k_scan1<<<B_, 128, 0, stream>>>(Base, T2, Evcol, argw, Snap, MaskSnap);
    k_scan2<<<dim3(NCH, B_), 128, 0, stream>>>(T2, Evcol, argw, Snap, MaskSnap, argout);
}